// Round 5
// baseline (5664.431 us; speedup 1.0000x reference)
//
#include <hip/hip_runtime.h>
#include <hip/hip_cooperative_groups.h>

namespace cg = cooperative_groups;

typedef __attribute__((ext_vector_type(8))) short bf16x8;
typedef __attribute__((ext_vector_type(4))) float f32x4;
typedef __attribute__((ext_vector_type(4))) int   i32x4;

#define DEV static __device__ __forceinline__

constexpr int BATCH = 512;
constexpr int TENC  = 64;
constexpr int DIN   = 512;
constexpr int HDIM  = 512;
constexpr int NCLS  = 38;
constexpr int STEPS = 26;
constexpr int NG    = 4 * HDIM;   // 2048

// ---- workspace layout (bytes); every size is 4096-aligned ----
constexpr size_t HP_OFF   = 0;                                   // bf16 [B*T][512]  H_proj
constexpr size_t HP_SZ    = (size_t)BATCH * TENC * HDIM * 2;
constexpr size_t ENC_OFF  = HP_OFF + HP_SZ;                      // bf16 [B*T][512]  encoder
constexpr size_t ENC_SZ   = (size_t)BATCH * TENC * DIN * 2;
constexpr size_t A2_OFF   = ENC_OFF + ENC_SZ;                    // bf16 [2][B][1024] ping-pong [ctx | h]
constexpr size_t A2_SZ    = (size_t)2 * BATCH * 1024 * 2;
constexpr size_t C32_OFF  = A2_OFF + A2_SZ;                      // f32 [B][512]     cell state
constexpr size_t C32_SZ   = (size_t)BATCH * HDIM * 4;
constexpr size_t HP32_OFF = C32_OFF + C32_SZ;                    // f32 [B][512]     h@w_h2h.T + b
constexpr size_t HP32_SZ  = (size_t)BATCH * HDIM * 4;
constexpr size_t B2R_OFF  = HP32_OFF + HP32_SZ;                  // bf16 [2048][1024] [w_ih_d | w_hh], gate-interleaved
constexpr size_t B2R_SZ   = (size_t)NG * 1024 * 2;
constexpr size_t WI2H_OFF = B2R_OFF + B2R_SZ;                    // bf16 [512][512]
constexpr size_t WI2H_SZ  = (size_t)HDIM * DIN * 2;
constexpr size_t B3_OFF   = WI2H_OFF + WI2H_SZ;                  // bf16 [576][512]  [w_h2h ; w_gen ; pad]
constexpr size_t B3_SZ    = (size_t)576 * HDIM * 2;
constexpr size_t WOH_OFF  = B3_OFF + B3_SZ;                      // f32 [2048][38]   one-hot columns, interleaved
constexpr size_t WOH_SZ   = (size_t)NG * NCLS * 4;
constexpr size_t BIAS_OFF = WOH_OFF + WOH_SZ;                    // f32 [2048]       b_ih+b_hh interleaved
constexpr size_t BIAS_SZ  = (size_t)NG * 4;
constexpr size_t HSEQ_OFF = BIAS_OFF + BIAS_SZ;                  // bf16 [S][B][512] hidden log
constexpr size_t HSEQ_SZ  = (size_t)STEPS * BATCH * HDIM * 2;

DEV float bf2f(unsigned short s) {
    unsigned u = ((unsigned)s) << 16;
    return __builtin_bit_cast(float, u);
}
DEV unsigned short f2bf(float f) {
    unsigned u = __builtin_bit_cast(unsigned, f);
    u = (u + 0x7fffu + ((u >> 16) & 1u)) >> 16;   // RNE
    return (unsigned short)u;
}
DEV float sigmoid_f(float x) { return 1.f / (1.f + __expf(-x)); }
DEV float tanh_f(float x) {
    x = fminf(fmaxf(x, -15.f), 15.f);
    float e = __expf(2.f * x);
    return (e - 1.f) / (e + 1.f);
}

// ---------------- conversion / init kernels ----------------
__global__ void conv_bf16_kernel(const float* __restrict__ in,
                                 unsigned short* __restrict__ out, int n4) {
    int i = blockIdx.x * blockDim.x + threadIdx.x;
    int stride = gridDim.x * blockDim.x;
    for (; i < n4; i += stride) {
        float4 v = ((const float4*)in)[i];
        ushort4 o;
        o.x = f2bf(v.x); o.y = f2bf(v.y); o.z = f2bf(v.z); o.w = f2bf(v.w);
        ((ushort4*)out)[i] = o;
    }
}

__global__ void build_b2r_kernel(const float* __restrict__ w_ih, const float* __restrict__ w_hh,
                                 const float* __restrict__ b_ih, const float* __restrict__ b_hh,
                                 unsigned short* __restrict__ B2r, float* __restrict__ woh,
                                 float* __restrict__ bias2r) {
    int np = blockIdx.x;            // 0..2047 (n' = u*4+g)
    int u = np >> 2, g = np & 3;
    int src = g * 512 + u;
    for (int k = threadIdx.x; k < 512; k += blockDim.x) {
        B2r[np * 1024 + k]       = f2bf(w_ih[src * 550 + k]);
        B2r[np * 1024 + 512 + k] = f2bf(w_hh[src * 512 + k]);
    }
    if (threadIdx.x < NCLS) woh[np * NCLS + threadIdx.x] = w_ih[src * 550 + 512 + threadIdx.x];
    if (threadIdx.x == 0)   bias2r[np] = b_ih[src] + b_hh[src];
}

__global__ void build_b3_kernel(const float* __restrict__ w_h2h, const float* __restrict__ w_gen,
                                unsigned short* __restrict__ B3) {
    int n = blockIdx.x;             // 0..575
    for (int k = threadIdx.x; k < 512; k += blockDim.x) {
        float v = 0.f;
        if (n < 512)      v = w_h2h[n * 512 + k];
        else if (n < 550) v = w_gen[(n - 512) * 512 + k];
        B3[n * 512 + k] = f2bf(v);
    }
}

__global__ void init_state_kernel(float* __restrict__ c32, float* __restrict__ hp32,
                                  unsigned short* __restrict__ A2,
                                  const float* __restrict__ b_h2h) {
    int b = blockIdx.x;
    for (int j = threadIdx.x; j < 512; j += blockDim.x) {
        c32[b * 512 + j]  = 0.f;
        hp32[b * 512 + j] = b_h2h[j];          // h0 = 0 -> hp = b_h2h
        A2[b * 1024 + 512 + j] = 0;            // h part of buffer 0 = 0
    }
}

// ---------------- generic MFMA GEMM core ----------------
// C[m0:BM, n0:BN] += A[M,K] * B[N,K]^T ; A,B row-major bf16; 4 waves arranged
// (4/WN) x WN; wave tile = (FRM*16) x (FRN*16). BK=32, LDS row stride 40.
template<int BM, int BN, int WN, int FRM, int FRN>
DEV void gemm_core(const unsigned short* __restrict__ A, int ldA,
                   const unsigned short* __restrict__ Bm, int ldB, int K,
                   int m0, int n0, unsigned short* __restrict__ lA,
                   unsigned short* __restrict__ lB, f32x4 acc[FRM][FRN]) {
    constexpr int LSTR = 40;  // 80B rows: 16B aligned, ~2-way banks on b128 reads
    const int tid  = threadIdx.x;
    const int lane = tid & 63;
    const int wid  = tid >> 6;
    const int wm = wid / WN, wn = wid % WN;
    const int fr_row = lane & 15;
    const int fr_kb  = (lane >> 4) * 8;

    for (int k0 = 0; k0 < K; k0 += 32) {
        #pragma unroll
        for (int u = tid; u < BM * 4; u += 256) {
            int r = u >> 2, cb = u & 3;
            *(i32x4*)(lA + r * LSTR + cb * 8) =
                *(const i32x4*)(A + (size_t)(m0 + r) * ldA + k0 + cb * 8);
        }
        #pragma unroll
        for (int u = tid; u < BN * 4; u += 256) {
            int r = u >> 2, cb = u & 3;
            *(i32x4*)(lB + r * LSTR + cb * 8) =
                *(const i32x4*)(Bm + (size_t)(n0 + r) * ldB + k0 + cb * 8);
        }
        __syncthreads();
        bf16x8 af[FRM], bfv[FRN];
        #pragma unroll
        for (int i = 0; i < FRM; i++)
            af[i] = *(const bf16x8*)(lA + (wm * FRM * 16 + i * 16 + fr_row) * LSTR + fr_kb);
        #pragma unroll
        for (int j = 0; j < FRN; j++)
            bfv[j] = *(const bf16x8*)(lB + (wn * FRN * 16 + j * 16 + fr_row) * LSTR + fr_kb);
        #pragma unroll
        for (int i = 0; i < FRM; i++)
            #pragma unroll
            for (int j = 0; j < FRN; j++)
                acc[i][j] = __builtin_amdgcn_mfma_f32_16x16x32_bf16(af[i], bfv[j], acc[i][j], 0, 0, 0);
        __syncthreads();
    }
}

// ---------------- H_proj GEMM (bf16 output) ----------------
__global__ __launch_bounds__(256) void gemm_bf16out_kernel(
    const unsigned short* __restrict__ A, int ldA,
    const unsigned short* __restrict__ Bm, int ldB,
    unsigned short* __restrict__ C, int ldC, int K) {
    constexpr int BM = 128, BN = 128, FRM = 4, FRN = 4;
    __shared__ __align__(16) unsigned short lA[BM * 40], lB[BN * 40];
    int m0 = blockIdx.x * BM, n0 = blockIdx.y * BN;
    f32x4 acc[FRM][FRN] = {};
    gemm_core<BM, BN, 2, FRM, FRN>(A, ldA, Bm, ldB, K, m0, n0, lA, lB, acc);
    const int lane = threadIdx.x & 63, wid = threadIdx.x >> 6;
    const int wm = wid >> 1, wn = wid & 1;
    #pragma unroll
    for (int i = 0; i < FRM; i++)
        #pragma unroll
        for (int j = 0; j < FRN; j++)
            #pragma unroll
            for (int r = 0; r < 4; r++) {
                int m = m0 + wm * FRM * 16 + i * 16 + (lane >> 4) * 4 + r;
                int n = n0 + wn * FRN * 16 + j * 16 + (lane & 15);
                C[(size_t)m * ldC + n] = f2bf(acc[i][j][r]);
            }
}

// ---------------- final probs GEMM: hseq @ [w_gen;0]^T ----------------
__global__ __launch_bounds__(256) void probs_kernel(
    const unsigned short* __restrict__ hseq,   // [S*B][512] bf16
    const unsigned short* __restrict__ Bg,     // [64][512]  bf16 (w_gen padded)
    const float* __restrict__ b_gen, float* __restrict__ out) {
    __shared__ __align__(16) unsigned short lA[64 * 40], lB[64 * 40];
    int m0 = blockIdx.x * 64;
    f32x4 acc[2][2] = {};
    gemm_core<64, 64, 2, 2, 2>(hseq, 512, Bg, 512, 512, m0, 0, lA, lB, acc);
    const int lane = threadIdx.x & 63, wid = threadIdx.x >> 6;
    const int wm = wid >> 1, wn = wid & 1;
    #pragma unroll
    for (int i = 0; i < 2; i++)
        #pragma unroll
        for (int j = 0; j < 2; j++)
            #pragma unroll
            for (int r = 0; r < 4; r++) {
                int m = m0 + wm * 32 + i * 16 + (lane >> 4) * 4 + r;
                int n = wn * 32 + j * 16 + (lane & 15);
                if (n < NCLS) {
                    int ss = m >> 9, b = m & 511;   // hseq row = s*512 + b
                    out[((size_t)b * STEPS + ss) * NCLS + n] = acc[i][j][r] + b_gen[n];
                }
            }
}

// ---------------- cooperative decode kernel: all 26 steps ----------------
// grid = 512 blocks x 256 threads, co-resident (2 blocks/CU).
__global__ __launch_bounds__(256, 2) void decode_kernel(
    const unsigned short* __restrict__ Hp,
    const unsigned short* __restrict__ enc,
    unsigned short* __restrict__ A2,       // [2][B][1024]
    float* __restrict__ c32,
    float* __restrict__ hp32,
    const unsigned short* __restrict__ B2r,
    const float* __restrict__ bias2r,
    const float* __restrict__ woh,
    const unsigned short* __restrict__ B3,
    const float* __restrict__ b_h2h,
    const float* __restrict__ w_score,
    const int* __restrict__ text,
    unsigned short* __restrict__ hseq) {
    cg::grid_group grid = cg::this_grid();
    __shared__ __align__(16) char smem[17920];
    const int bid  = blockIdx.x;
    const int tid  = threadIdx.x;
    const int lane = tid & 63, wid = tid >> 6;

    for (int s = 0; s < STEPS; ++s) {
        unsigned short* A2cur = A2 + (size_t)(s & 1) * BATCH * 1024;
        unsigned short* A2nxt = A2 + (size_t)((s + 1) & 1) * BATCH * 1024;

        // ---- phase 1: attention; block = batch row ----
        {
            float* e_lds = (float*)smem;
            float* alpha_lds = e_lds + 64;
            const int b = bid;
            float hp8[8], ws8[8];
            {
                const float4* hp4 = (const float4*)(hp32 + b * 512 + lane * 8);
                const float4* ws4 = (const float4*)(w_score + lane * 8);
                float4 h0 = hp4[0], h1 = hp4[1], w0 = ws4[0], w1 = ws4[1];
                hp8[0] = h0.x; hp8[1] = h0.y; hp8[2] = h0.z; hp8[3] = h0.w;
                hp8[4] = h1.x; hp8[5] = h1.y; hp8[6] = h1.z; hp8[7] = h1.w;
                ws8[0] = w0.x; ws8[1] = w0.y; ws8[2] = w0.z; ws8[3] = w0.w;
                ws8[4] = w1.x; ws8[5] = w1.y; ws8[6] = w1.z; ws8[7] = w1.w;
            }
            for (int t = wid; t < 64; t += 4) {
                bf16x8 hv = *(const bf16x8*)(Hp + ((size_t)b * 64 + t) * 512 + lane * 8);
                float a = 0.f;
                #pragma unroll
                for (int j = 0; j < 8; j++)
                    a += ws8[j] * tanh_f(hp8[j] + bf2f((unsigned short)hv[j]));
                #pragma unroll
                for (int off = 32; off > 0; off >>= 1) a += __shfl_down(a, off);
                if (lane == 0) e_lds[t] = a;
            }
            __syncthreads();
            if (wid == 0) {
                float v = e_lds[lane];
                float m = v;
                #pragma unroll
                for (int off = 32; off > 0; off >>= 1) m = fmaxf(m, __shfl_xor(m, off));
                float ex = __expf(v - m);
                float sum = ex;
                #pragma unroll
                for (int off = 32; off > 0; off >>= 1) sum += __shfl_xor(sum, off);
                alpha_lds[lane] = ex / sum;
            }
            __syncthreads();
            float a0 = 0.f, a1 = 0.f;
            const unsigned short* erow = enc + (size_t)b * 64 * 512 + tid * 2;
            #pragma unroll 8
            for (int t = 0; t < 64; t++) {
                float al = alpha_lds[t];
                unsigned pv = *(const unsigned*)(erow + (size_t)t * 512);
                a0 += al * bf2f((unsigned short)(pv & 0xffffu));
                a1 += al * bf2f((unsigned short)(pv >> 16));
            }
            unsigned short o0 = f2bf(a0), o1 = f2bf(a1);
            *(unsigned*)(A2cur + (size_t)b * 1024 + tid * 2) = ((unsigned)o1 << 16) | (unsigned)o0;
        }
        grid.sync();

        // ---- phase 2: gates GEMM + LSTM pointwise; 512 blocks, 64x32 tiles ----
        {
            unsigned short* lA = (unsigned short*)smem;          // 64*40*2 = 5120 B
            unsigned short* lB = lA + 64 * 40;                   // 32*40*2 = 2560 B
            float* gbuf = (float*)(smem + 7680);                 // [64][36] = 9216 B
            const int m0 = (bid >> 6) * 64, n0 = (bid & 63) * 32;
            f32x4 acc[2][1] = {};
            gemm_core<64, 32, 2, 2, 1>(A2cur, 1024, B2r, 1024, 1024, m0, n0, lA, lB, acc);
            const int wm = wid >> 1, wn = wid & 1;
            #pragma unroll
            for (int i = 0; i < 2; i++)
                #pragma unroll
                for (int r = 0; r < 4; r++) {
                    int ml = wm * 32 + i * 16 + (lane >> 4) * 4 + r;
                    int nl = wn * 16 + (lane & 15);
                    gbuf[ml * 36 + nl] = acc[i][0][r];
                }
            __syncthreads();
            for (int idx = tid; idx < 64 * 8; idx += 256) {
                int rl = idx >> 3, uu = idx & 7;
                int b  = m0 + rl;
                int nb = n0 + uu * 4;
                int u  = nb >> 2;
                int tb = text[b * STEPS + s];
                float4 g4 = *(const float4*)(gbuf + rl * 36 + uu * 4);
                float vi = g4.x + bias2r[nb + 0] + woh[(nb + 0) * NCLS + tb];
                float vf = g4.y + bias2r[nb + 1] + woh[(nb + 1) * NCLS + tb];
                float vg = g4.z + bias2r[nb + 2] + woh[(nb + 2) * NCLS + tb];
                float vo = g4.w + bias2r[nb + 3] + woh[(nb + 3) * NCLS + tb];
                float c_old = c32[b * 512 + u];
                float cn = sigmoid_f(vf) * c_old + sigmoid_f(vi) * tanh_f(vg);
                float hn = sigmoid_f(vo) * tanh_f(cn);
                c32[b * 512 + u] = cn;
                unsigned short hb = f2bf(hn);
                A2nxt[(size_t)b * 1024 + 512 + u] = hb;
                hseq[((size_t)s * BATCH + b) * 512 + u] = hb;
            }
        }
        grid.sync();

        // ---- phase 3: hp = h_new @ w_h2h^T + b_h2h (skipped on last step) ----
        if (s + 1 < STEPS) {
            if (bid < 256) {
                unsigned short* lA = (unsigned short*)smem;
                unsigned short* lB = lA + 32 * 40;
                const int m0 = (bid >> 4) * 32, n0 = (bid & 15) * 32;
                f32x4 acc[1][1] = {};
                gemm_core<32, 32, 2, 1, 1>(A2nxt + 512, 1024, B3, 512, 512, m0, n0, lA, lB, acc);
                const int wm = wid >> 1, wn = wid & 1;
                #pragma unroll
                for (int r = 0; r < 4; r++) {
                    int m = m0 + wm * 16 + (lane >> 4) * 4 + r;
                    int n = n0 + wn * 16 + (lane & 15);
                    hp32[m * 512 + n] = acc[0][0][r] + b_h2h[n];
                }
            }
            grid.sync();
        }
    }
}

// ---------------- host ----------------
extern "C" void kernel_launch(void* const* d_in, const int* in_sizes, int n_in,
                              void* d_out, int out_size, void* d_ws, size_t ws_size,
                              hipStream_t stream) {
    (void)in_sizes; (void)n_in; (void)out_size; (void)ws_size;
    const float* enc_f   = (const float*)d_in[0];
    const int*   text    = (const int*)d_in[1];
    const float* w_i2h   = (const float*)d_in[2];
    const float* w_h2h   = (const float*)d_in[3];
    const float* b_h2h   = (const float*)d_in[4];
    const float* w_score = (const float*)d_in[5];
    const float* w_ih    = (const float*)d_in[6];
    const float* w_hh    = (const float*)d_in[7];
    const float* b_ih    = (const float*)d_in[8];
    const float* b_hh    = (const float*)d_in[9];
    const float* w_gen   = (const float*)d_in[10];
    const float* b_gen   = (const float*)d_in[11];
    float* out = (float*)d_out;

    char* ws = (char*)d_ws;
    const unsigned short* Hp     = (const unsigned short*)(ws + HP_OFF);
    unsigned short*       Hp_w   = (unsigned short*)(ws + HP_OFF);
    const unsigned short* encb   = (const unsigned short*)(ws + ENC_OFF);
    unsigned short*       encb_w = (unsigned short*)(ws + ENC_OFF);
    unsigned short*       A2     = (unsigned short*)(ws + A2_OFF);
    float*                c32    = (float*)(ws + C32_OFF);
    float*                hp32   = (float*)(ws + HP32_OFF);
    const unsigned short* B2r    = (const unsigned short*)(ws + B2R_OFF);
    unsigned short*       B2r_w  = (unsigned short*)(ws + B2R_OFF);
    unsigned short*       wi2hb  = (unsigned short*)(ws + WI2H_OFF);
    const unsigned short* B3     = (const unsigned short*)(ws + B3_OFF);
    unsigned short*       B3_w   = (unsigned short*)(ws + B3_OFF);
    const float*          woh    = (const float*)(ws + WOH_OFF);
    float*                woh_w  = (float*)(ws + WOH_OFF);
    const float*          bias2r = (const float*)(ws + BIAS_OFF);
    float*                bias2r_w = (float*)(ws + BIAS_OFF);
    unsigned short*       hseq   = (unsigned short*)(ws + HSEQ_OFF);

    conv_bf16_kernel<<<2048, 256, 0, stream>>>(enc_f, encb_w, BATCH * TENC * DIN / 4);
    conv_bf16_kernel<<<256, 256, 0, stream>>>(w_i2h, wi2hb, HDIM * DIN / 4);
    build_b2r_kernel<<<NG, 256, 0, stream>>>(w_ih, w_hh, b_ih, b_hh, B2r_w, woh_w, bias2r_w);
    build_b3_kernel<<<576, 256, 0, stream>>>(w_h2h, w_gen, B3_w);
    init_state_kernel<<<BATCH, 256, 0, stream>>>(c32, hp32, A2, b_h2h);

    // H_proj = enc @ w_i2h^T  (M=32768, N=512, K=512)
    gemm_bf16out_kernel<<<dim3(BATCH * TENC / 128, HDIM / 128), 256, 0, stream>>>(
        encb, DIN, wi2hb, DIN, Hp_w, HDIM, DIN);

    // cooperative decode: all 26 steps in one launch
    {
        void* args[13] = {
            (void*)&Hp, (void*)&encb, (void*)&A2, (void*)&c32, (void*)&hp32,
            (void*)&B2r, (void*)&bias2r, (void*)&woh, (void*)&B3,
            (void*)&b_h2h, (void*)&w_score, (void*)&text, (void*)&hseq
        };
        hipLaunchCooperativeKernel((const void*)decode_kernel, dim3(512), dim3(256),
                                   args, 0, stream);
    }

    // probs = hseq @ [w_gen;0]^T + b_gen  (M = S*B = 13312, N = 64, K = 512)
    probs_kernel<<<dim3(STEPS * BATCH / 64), 256, 0, stream>>>(
        hseq, B3 + (size_t)512 * 512, b_gen, out);
}

// Round 6
// 2667.914 us; speedup vs baseline: 2.1232x; 2.1232x over previous
//
#include <hip/hip_runtime.h>

typedef __attribute__((ext_vector_type(8))) short bf16x8;
typedef __attribute__((ext_vector_type(4))) float f32x4;
typedef __attribute__((ext_vector_type(4))) int   i32x4;

#define DEV static __device__ __forceinline__

constexpr int BATCH = 512;
constexpr int TENC  = 64;
constexpr int DIN   = 512;
constexpr int HDIM  = 512;
constexpr int NCLS  = 38;
constexpr int STEPS = 26;
constexpr int NG    = 4 * HDIM;   // 2048

// ---- workspace layout (bytes) ----
constexpr size_t HP_OFF   = 0;                                   // bf16 [B*T][512]  H_proj
constexpr size_t HP_SZ    = (size_t)BATCH * TENC * HDIM * 2;
constexpr size_t ENC_OFF  = HP_OFF + HP_SZ;                      // bf16 [B*T][512]  encoder
constexpr size_t ENC_SZ   = (size_t)BATCH * TENC * DIN * 2;
constexpr size_t A2_OFF   = ENC_OFF + ENC_SZ;                    // bf16 [2][B][1024] ping-pong [ctx | h]
constexpr size_t A2_SZ    = (size_t)2 * BATCH * 1024 * 2;
constexpr size_t C32_OFF  = A2_OFF + A2_SZ;                      // f32 [B][512]     cell state
constexpr size_t C32_SZ   = (size_t)BATCH * HDIM * 4;
constexpr size_t HP32_OFF = C32_OFF + C32_SZ;                    // f32 [B][512]     h@w_h2h.T + b
constexpr size_t HP32_SZ  = (size_t)BATCH * HDIM * 4;
constexpr size_t B2R_OFF  = HP32_OFF + HP32_SZ;                  // bf16 [2048][1024] gate-interleaved
constexpr size_t B2R_SZ   = (size_t)NG * 1024 * 2;
constexpr size_t WI2H_OFF = B2R_OFF + B2R_SZ;                    // bf16 [512][512]
constexpr size_t WI2H_SZ  = (size_t)HDIM * DIN * 2;
constexpr size_t B3_OFF   = WI2H_OFF + WI2H_SZ;                  // bf16 [576][512]  [w_h2h ; w_gen ; pad]
constexpr size_t B3_SZ    = (size_t)576 * HDIM * 2;
constexpr size_t WOH_OFF  = B3_OFF + B3_SZ;                      // f32 [2048][38]
constexpr size_t WOH_SZ   = (size_t)NG * NCLS * 4;
constexpr size_t BIAS_OFF = WOH_OFF + WOH_SZ;                    // f32 [2048]
constexpr size_t BIAS_SZ  = (size_t)NG * 4;
constexpr size_t HSEQ_OFF = BIAS_OFF + BIAS_SZ;                  // bf16 [S][B][512]
constexpr size_t HSEQ_SZ  = (size_t)STEPS * BATCH * HDIM * 2;
constexpr size_t BAR_OFF  = HSEQ_OFF + HSEQ_SZ;                  // u32[520] barrier state
constexpr size_t BAR_SZ   = 4096;

DEV float bf2f(unsigned short s) {
    unsigned u = ((unsigned)s) << 16;
    return __builtin_bit_cast(float, u);
}
DEV unsigned short f2bf(float f) {
    unsigned u = __builtin_bit_cast(unsigned, f);
    u = (u + 0x7fffu + ((u >> 16) & 1u)) >> 16;   // RNE
    return (unsigned short)u;
}
DEV float sigmoid_f(float x) { return 1.f / (1.f + __expf(-x)); }
DEV float tanh_f(float x) {
    x = fminf(fmaxf(x, -15.f), 15.f);
    float e = __expf(2.f * x);
    return (e - 1.f) / (e + 1.f);
}

// ---------- custom grid barrier ----------
// bar layout (uints): sub counters at i*32 (i=0..7, 64 arrivals each),
// root at 256, gen replicas at 288 + i*32. All zeroed by init_state_kernel.
DEV void gbar(unsigned* bar, int bid) {
    __syncthreads();
    if (threadIdx.x == 0) {
        __builtin_amdgcn_fence(__ATOMIC_RELEASE, "agent");   // publish this block's writes
        const int sg = bid & 7;
        unsigned* sub  = bar + sg * 32;
        unsigned* root = bar + 256;
        unsigned* genp = bar + 288 + sg * 32;
        unsigned g = __hip_atomic_load(genp, __ATOMIC_RELAXED, __HIP_MEMORY_SCOPE_AGENT);
        bool spin = true;
        if (__hip_atomic_fetch_add(sub, 1u, __ATOMIC_RELAXED, __HIP_MEMORY_SCOPE_AGENT) == 63u) {
            if (__hip_atomic_fetch_add(root, 1u, __ATOMIC_RELAXED, __HIP_MEMORY_SCOPE_AGENT) == 7u) {
                // last block overall: reset counters, then flip all gen replicas
                #pragma unroll
                for (int i = 0; i < 8; i++)
                    __hip_atomic_store(bar + i * 32, 0u, __ATOMIC_RELAXED, __HIP_MEMORY_SCOPE_AGENT);
                __hip_atomic_store(root, 0u, __ATOMIC_RELAXED, __HIP_MEMORY_SCOPE_AGENT);
                #pragma unroll
                for (int i = 0; i < 8; i++)
                    __hip_atomic_store(bar + 288 + i * 32, g + 1u, __ATOMIC_RELEASE, __HIP_MEMORY_SCOPE_AGENT);
                spin = false;
            }
        }
        if (spin) {
            while (__hip_atomic_load(genp, __ATOMIC_RELAXED, __HIP_MEMORY_SCOPE_AGENT) == g)
                __builtin_amdgcn_s_sleep(1);
        }
        __builtin_amdgcn_fence(__ATOMIC_ACQUIRE, "agent");   // see other blocks' writes
    }
    __syncthreads();
}

// ---------------- conversion / init kernels ----------------
__global__ void conv_bf16_kernel(const float* __restrict__ in,
                                 unsigned short* __restrict__ out, int n4) {
    int i = blockIdx.x * blockDim.x + threadIdx.x;
    int stride = gridDim.x * blockDim.x;
    for (; i < n4; i += stride) {
        float4 v = ((const float4*)in)[i];
        ushort4 o;
        o.x = f2bf(v.x); o.y = f2bf(v.y); o.z = f2bf(v.z); o.w = f2bf(v.w);
        ((ushort4*)out)[i] = o;
    }
}

__global__ void build_b2r_kernel(const float* __restrict__ w_ih, const float* __restrict__ w_hh,
                                 const float* __restrict__ b_ih, const float* __restrict__ b_hh,
                                 unsigned short* __restrict__ B2r, float* __restrict__ woh,
                                 float* __restrict__ bias2r) {
    int np = blockIdx.x;            // 0..2047 (n' = u*4+g)
    int u = np >> 2, g = np & 3;
    int src = g * 512 + u;
    for (int k = threadIdx.x; k < 512; k += blockDim.x) {
        B2r[np * 1024 + k]       = f2bf(w_ih[src * 550 + k]);
        B2r[np * 1024 + 512 + k] = f2bf(w_hh[src * 512 + k]);
    }
    if (threadIdx.x < NCLS) woh[np * NCLS + threadIdx.x] = w_ih[src * 550 + 512 + threadIdx.x];
    if (threadIdx.x == 0)   bias2r[np] = b_ih[src] + b_hh[src];
}

__global__ void build_b3_kernel(const float* __restrict__ w_h2h, const float* __restrict__ w_gen,
                                unsigned short* __restrict__ B3) {
    int n = blockIdx.x;             // 0..575
    for (int k = threadIdx.x; k < 512; k += blockDim.x) {
        float v = 0.f;
        if (n < 512)      v = w_h2h[n * 512 + k];
        else if (n < 550) v = w_gen[(n - 512) * 512 + k];
        B3[n * 512 + k] = f2bf(v);
    }
}

__global__ void init_state_kernel(float* __restrict__ c32, float* __restrict__ hp32,
                                  unsigned short* __restrict__ A2,
                                  const float* __restrict__ b_h2h,
                                  unsigned* __restrict__ bar) {
    int b = blockIdx.x;
    for (int j = threadIdx.x; j < 512; j += blockDim.x) {
        c32[b * 512 + j]  = 0.f;
        hp32[b * 512 + j] = b_h2h[j];          // h0 = 0 -> hp = b_h2h
        A2[b * 1024 + 512 + j] = 0;            // h part of buffer 0 = 0
    }
    if (b == 0)
        for (int j = threadIdx.x; j < 520; j += blockDim.x) bar[j] = 0;
}

// ---------------- generic MFMA GEMM core ----------------
template<int BM, int BN, int WN, int FRM, int FRN>
DEV void gemm_core(const unsigned short* __restrict__ A, int ldA,
                   const unsigned short* __restrict__ Bm, int ldB, int K,
                   int m0, int n0, unsigned short* __restrict__ lA,
                   unsigned short* __restrict__ lB, f32x4 acc[FRM][FRN]) {
    constexpr int LSTR = 40;
    const int tid  = threadIdx.x;
    const int lane = tid & 63;
    const int wid  = tid >> 6;
    const int wm = wid / WN, wn = wid % WN;
    const int fr_row = lane & 15;
    const int fr_kb  = (lane >> 4) * 8;

    for (int k0 = 0; k0 < K; k0 += 32) {
        #pragma unroll
        for (int u = tid; u < BM * 4; u += 256) {
            int r = u >> 2, cb = u & 3;
            *(i32x4*)(lA + r * LSTR + cb * 8) =
                *(const i32x4*)(A + (size_t)(m0 + r) * ldA + k0 + cb * 8);
        }
        #pragma unroll
        for (int u = tid; u < BN * 4; u += 256) {
            int r = u >> 2, cb = u & 3;
            *(i32x4*)(lB + r * LSTR + cb * 8) =
                *(const i32x4*)(Bm + (size_t)(n0 + r) * ldB + k0 + cb * 8);
        }
        __syncthreads();
        bf16x8 af[FRM], bfv[FRN];
        #pragma unroll
        for (int i = 0; i < FRM; i++)
            af[i] = *(const bf16x8*)(lA + (wm * FRM * 16 + i * 16 + fr_row) * LSTR + fr_kb);
        #pragma unroll
        for (int j = 0; j < FRN; j++)
            bfv[j] = *(const bf16x8*)(lB + (wn * FRN * 16 + j * 16 + fr_row) * LSTR + fr_kb);
        #pragma unroll
        for (int i = 0; i < FRM; i++)
            #pragma unroll
            for (int j = 0; j < FRN; j++)
                acc[i][j] = __builtin_amdgcn_mfma_f32_16x16x32_bf16(af[i], bfv[j], acc[i][j], 0, 0, 0);
        __syncthreads();
    }
}

// ---------------- H_proj GEMM (bf16 output) ----------------
__global__ __launch_bounds__(256) void gemm_bf16out_kernel(
    const unsigned short* __restrict__ A, int ldA,
    const unsigned short* __restrict__ Bm, int ldB,
    unsigned short* __restrict__ C, int ldC, int K) {
    constexpr int BM = 128, BN = 128, FRM = 4, FRN = 4;
    __shared__ __align__(16) unsigned short lA[BM * 40], lB[BN * 40];
    int m0 = blockIdx.x * BM, n0 = blockIdx.y * BN;
    f32x4 acc[FRM][FRN] = {};
    gemm_core<BM, BN, 2, FRM, FRN>(A, ldA, Bm, ldB, K, m0, n0, lA, lB, acc);
    const int lane = threadIdx.x & 63, wid = threadIdx.x >> 6;
    const int wm = wid >> 1, wn = wid & 1;
    #pragma unroll
    for (int i = 0; i < FRM; i++)
        #pragma unroll
        for (int j = 0; j < FRN; j++)
            #pragma unroll
            for (int r = 0; r < 4; r++) {
                int m = m0 + wm * FRM * 16 + i * 16 + (lane >> 4) * 4 + r;
                int n = n0 + wn * FRN * 16 + j * 16 + (lane & 15);
                C[(size_t)m * ldC + n] = f2bf(acc[i][j][r]);
            }
}

// ---------------- final probs GEMM ----------------
__global__ __launch_bounds__(256) void probs_kernel(
    const unsigned short* __restrict__ hseq,   // [S*B][512] bf16
    const unsigned short* __restrict__ Bg,     // [64][512]  bf16 (w_gen padded)
    const float* __restrict__ b_gen, float* __restrict__ out) {
    __shared__ __align__(16) unsigned short lA[64 * 40], lB[64 * 40];
    int m0 = blockIdx.x * 64;
    f32x4 acc[2][2] = {};
    gemm_core<64, 64, 2, 2, 2>(hseq, 512, Bg, 512, 512, m0, 0, lA, lB, acc);
    const int lane = threadIdx.x & 63, wid = threadIdx.x >> 6;
    const int wm = wid >> 1, wn = wid & 1;
    #pragma unroll
    for (int i = 0; i < 2; i++)
        #pragma unroll
        for (int j = 0; j < 2; j++)
            #pragma unroll
            for (int r = 0; r < 4; r++) {
                int m = m0 + wm * 32 + i * 16 + (lane >> 4) * 4 + r;
                int n = wn * 32 + j * 16 + (lane & 15);
                if (n < NCLS) {
                    int ss = m >> 9, b = m & 511;   // hseq row = s*512 + b
                    out[((size_t)b * STEPS + ss) * NCLS + n] = acc[i][j][r] + b_gen[n];
                }
            }
}

// ---------------- cooperative decode kernel: all 26 steps ----------------
__global__ __launch_bounds__(256, 2) void decode_kernel(
    const unsigned short* __restrict__ Hp,
    const unsigned short* __restrict__ enc,
    unsigned short* __restrict__ A2,       // [2][B][1024]
    float* __restrict__ c32,
    float* __restrict__ hp32,
    const unsigned short* __restrict__ B2r,
    const float* __restrict__ bias2r,
    const float* __restrict__ woh,
    const unsigned short* __restrict__ B3,
    const float* __restrict__ b_h2h,
    const float* __restrict__ w_score,
    const int* __restrict__ text,
    unsigned short* __restrict__ hseq,
    unsigned* __restrict__ bar) {
    __shared__ __align__(16) char smem[17920];
    const int bid  = blockIdx.x;
    const int tid  = threadIdx.x;
    const int lane = tid & 63, wid = tid >> 6;

    for (int s = 0; s < STEPS; ++s) {
        unsigned short* A2cur = A2 + (size_t)(s & 1) * BATCH * 1024;
        unsigned short* A2nxt = A2 + (size_t)((s + 1) & 1) * BATCH * 1024;

        // ---- phase 1: attention; block = batch row ----
        {
            float* e_lds = (float*)smem;
            float* alpha_lds = e_lds + 64;
            const int b = bid;
            float hp8[8], ws8[8];
            {
                const float4* hp4 = (const float4*)(hp32 + b * 512 + lane * 8);
                const float4* ws4 = (const float4*)(w_score + lane * 8);
                float4 h0 = hp4[0], h1 = hp4[1], w0 = ws4[0], w1 = ws4[1];
                hp8[0] = h0.x; hp8[1] = h0.y; hp8[2] = h0.z; hp8[3] = h0.w;
                hp8[4] = h1.x; hp8[5] = h1.y; hp8[6] = h1.z; hp8[7] = h1.w;
                ws8[0] = w0.x; ws8[1] = w0.y; ws8[2] = w0.z; ws8[3] = w0.w;
                ws8[4] = w1.x; ws8[5] = w1.y; ws8[6] = w1.z; ws8[7] = w1.w;
            }
            for (int t = wid; t < 64; t += 4) {
                bf16x8 hv = *(const bf16x8*)(Hp + ((size_t)b * 64 + t) * 512 + lane * 8);
                float a = 0.f;
                #pragma unroll
                for (int j = 0; j < 8; j++)
                    a += ws8[j] * tanh_f(hp8[j] + bf2f((unsigned short)hv[j]));
                #pragma unroll
                for (int off = 32; off > 0; off >>= 1) a += __shfl_down(a, off);
                if (lane == 0) e_lds[t] = a;
            }
            __syncthreads();
            if (wid == 0) {
                float v = e_lds[lane];
                float m = v;
                #pragma unroll
                for (int off = 32; off > 0; off >>= 1) m = fmaxf(m, __shfl_xor(m, off));
                float ex = __expf(v - m);
                float sum = ex;
                #pragma unroll
                for (int off = 32; off > 0; off >>= 1) sum += __shfl_xor(sum, off);
                alpha_lds[lane] = ex / sum;
            }
            __syncthreads();
            float a0 = 0.f, a1 = 0.f;
            const unsigned short* erow = enc + (size_t)b * 64 * 512 + tid * 2;
            #pragma unroll 8
            for (int t = 0; t < 64; t++) {
                float al = alpha_lds[t];
                unsigned pv = *(const unsigned*)(erow + (size_t)t * 512);
                a0 += al * bf2f((unsigned short)(pv & 0xffffu));
                a1 += al * bf2f((unsigned short)(pv >> 16));
            }
            unsigned short o0 = f2bf(a0), o1 = f2bf(a1);
            *(unsigned*)(A2cur + (size_t)b * 1024 + tid * 2) = ((unsigned)o1 << 16) | (unsigned)o0;
        }
        gbar(bar, bid);

        // ---- phase 2: gates GEMM + LSTM pointwise; 512 blocks, 64x32 tiles ----
        {
            unsigned short* lA = (unsigned short*)smem;          // 64*40*2 = 5120 B
            unsigned short* lB = lA + 64 * 40;                   // 32*40*2 = 2560 B
            float* gbuf = (float*)(smem + 7680);                 // [64][36] = 9216 B
            const int m0 = (bid >> 6) * 64, n0 = (bid & 63) * 32;
            f32x4 acc[2][1] = {};
            gemm_core<64, 32, 2, 2, 1>(A2cur, 1024, B2r, 1024, 1024, m0, n0, lA, lB, acc);
            const int wm = wid >> 1, wn = wid & 1;
            #pragma unroll
            for (int i = 0; i < 2; i++)
                #pragma unroll
                for (int r = 0; r < 4; r++) {
                    int ml = wm * 32 + i * 16 + (lane >> 4) * 4 + r;
                    int nl = wn * 16 + (lane & 15);
                    gbuf[ml * 36 + nl] = acc[i][0][r];
                }
            __syncthreads();
            for (int idx = tid; idx < 64 * 8; idx += 256) {
                int rl = idx >> 3, uu = idx & 7;
                int b  = m0 + rl;
                int nb = n0 + uu * 4;
                int u  = nb >> 2;
                int tb = text[b * STEPS + s];
                float4 g4 = *(const float4*)(gbuf + rl * 36 + uu * 4);
                float vi = g4.x + bias2r[nb + 0] + woh[(nb + 0) * NCLS + tb];
                float vf = g4.y + bias2r[nb + 1] + woh[(nb + 1) * NCLS + tb];
                float vg = g4.z + bias2r[nb + 2] + woh[(nb + 2) * NCLS + tb];
                float vo = g4.w + bias2r[nb + 3] + woh[(nb + 3) * NCLS + tb];
                float c_old = c32[b * 512 + u];
                float cn = sigmoid_f(vf) * c_old + sigmoid_f(vi) * tanh_f(vg);
                float hn = sigmoid_f(vo) * tanh_f(cn);
                c32[b * 512 + u] = cn;
                unsigned short hb = f2bf(hn);
                A2nxt[(size_t)b * 1024 + 512 + u] = hb;
                hseq[((size_t)s * BATCH + b) * 512 + u] = hb;
            }
        }

        // ---- phase 3: hp = h_new @ w_h2h^T + b_h2h (skipped on last step) ----
        if (s + 1 < STEPS) {
            gbar(bar, bid);
            if (bid < 256) {
                unsigned short* lA = (unsigned short*)smem;
                unsigned short* lB = lA + 32 * 40;
                const int m0 = (bid >> 4) * 32, n0 = (bid & 15) * 32;
                f32x4 acc[1][1] = {};
                gemm_core<32, 32, 2, 1, 1>(A2nxt + 512, 1024, B3, 512, 512, m0, n0, lA, lB, acc);
                const int wm = wid >> 1, wn = wid & 1;
                #pragma unroll
                for (int r = 0; r < 4; r++) {
                    int m = m0 + wm * 16 + (lane >> 4) * 4 + r;
                    int n = n0 + wn * 16 + (lane & 15);
                    hp32[m * 512 + n] = acc[0][0][r] + b_h2h[n];
                }
            }
            gbar(bar, bid);
        }
    }
}

// ---------------- host ----------------
extern "C" void kernel_launch(void* const* d_in, const int* in_sizes, int n_in,
                              void* d_out, int out_size, void* d_ws, size_t ws_size,
                              hipStream_t stream) {
    (void)in_sizes; (void)n_in; (void)out_size; (void)ws_size;
    const float* enc_f   = (const float*)d_in[0];
    const int*   text    = (const int*)d_in[1];
    const float* w_i2h   = (const float*)d_in[2];
    const float* w_h2h   = (const float*)d_in[3];
    const float* b_h2h   = (const float*)d_in[4];
    const float* w_score = (const float*)d_in[5];
    const float* w_ih    = (const float*)d_in[6];
    const float* w_hh    = (const float*)d_in[7];
    const float* b_ih    = (const float*)d_in[8];
    const float* b_hh    = (const float*)d_in[9];
    const float* w_gen   = (const float*)d_in[10];
    const float* b_gen   = (const float*)d_in[11];
    float* out = (float*)d_out;

    char* ws = (char*)d_ws;
    const unsigned short* Hp     = (const unsigned short*)(ws + HP_OFF);
    unsigned short*       Hp_w   = (unsigned short*)(ws + HP_OFF);
    const unsigned short* encb   = (const unsigned short*)(ws + ENC_OFF);
    unsigned short*       encb_w = (unsigned short*)(ws + ENC_OFF);
    unsigned short*       A2     = (unsigned short*)(ws + A2_OFF);
    float*                c32    = (float*)(ws + C32_OFF);
    float*                hp32   = (float*)(ws + HP32_OFF);
    const unsigned short* B2r    = (const unsigned short*)(ws + B2R_OFF);
    unsigned short*       B2r_w  = (unsigned short*)(ws + B2R_OFF);
    unsigned short*       wi2hb  = (unsigned short*)(ws + WI2H_OFF);
    const unsigned short* B3     = (const unsigned short*)(ws + B3_OFF);
    unsigned short*       B3_w   = (unsigned short*)(ws + B3_OFF);
    const float*          woh    = (const float*)(ws + WOH_OFF);
    float*                woh_w  = (float*)(ws + WOH_OFF);
    const float*          bias2r = (const float*)(ws + BIAS_OFF);
    float*                bias2r_w = (float*)(ws + BIAS_OFF);
    unsigned short*       hseq   = (unsigned short*)(ws + HSEQ_OFF);
    unsigned*             bar    = (unsigned*)(ws + BAR_OFF);

    conv_bf16_kernel<<<2048, 256, 0, stream>>>(enc_f, encb_w, BATCH * TENC * DIN / 4);
    conv_bf16_kernel<<<256, 256, 0, stream>>>(w_i2h, wi2hb, HDIM * DIN / 4);
    build_b2r_kernel<<<NG, 256, 0, stream>>>(w_ih, w_hh, b_ih, b_hh, B2r_w, woh_w, bias2r_w);
    build_b3_kernel<<<576, 256, 0, stream>>>(w_h2h, w_gen, B3_w);
    init_state_kernel<<<BATCH, 256, 0, stream>>>(c32, hp32, A2, b_h2h, bar);

    // H_proj = enc @ w_i2h^T  (M=32768, N=512, K=512)
    gemm_bf16out_kernel<<<dim3(BATCH * TENC / 128, HDIM / 128), 256, 0, stream>>>(
        encb, DIN, wi2hb, DIN, Hp_w, HDIM, DIN);

    // cooperative decode: all 26 steps in one launch (custom barrier inside)
    {
        void* args[14] = {
            (void*)&Hp, (void*)&encb, (void*)&A2, (void*)&c32, (void*)&hp32,
            (void*)&B2r, (void*)&bias2r, (void*)&woh, (void*)&B3,
            (void*)&b_h2h, (void*)&w_score, (void*)&text, (void*)&hseq, (void*)&bar
        };
        hipLaunchCooperativeKernel((const void*)decode_kernel, dim3(512), dim3(256),
                                   args, 0, stream);
    }

    // probs = hseq @ [w_gen;0]^T + b_gen  (M = S*B = 13312, N = 64, K = 512)
    probs_kernel<<<dim3(STEPS * BATCH / 64), 256, 0, stream>>>(
        hseq, B3 + (size_t)512 * 512, b_gen, out);
}

// Round 7
// 1715.076 us; speedup vs baseline: 3.3027x; 1.5556x over previous
//
#include <hip/hip_runtime.h>

typedef __attribute__((ext_vector_type(8))) short bf16x8;
typedef __attribute__((ext_vector_type(4))) float f32x4;
typedef __attribute__((ext_vector_type(4))) int   i32x4;

#define DEV static __device__ __forceinline__

constexpr int BATCH = 512;
constexpr int TENC  = 64;
constexpr int DIN   = 512;
constexpr int HDIM  = 512;
constexpr int NCLS  = 38;
constexpr int STEPS = 26;
constexpr int NG    = 4 * HDIM;   // 2048

// ---- workspace layout (bytes) ----
constexpr size_t HP_OFF   = 0;                                   // bf16 [B*T][512]  H_proj
constexpr size_t HP_SZ    = (size_t)BATCH * TENC * HDIM * 2;
constexpr size_t ENC_OFF  = HP_OFF + HP_SZ;                      // bf16 [B*T][512]  encoder
constexpr size_t ENC_SZ   = (size_t)BATCH * TENC * DIN * 2;
constexpr size_t A2_OFF   = ENC_OFF + ENC_SZ;                    // bf16 [2][B][1024] ping-pong [ctx | h]
constexpr size_t A2_SZ    = (size_t)2 * BATCH * 1024 * 2;
constexpr size_t C32_OFF  = A2_OFF + A2_SZ;                      // f32 [B][512]     cell state (block-local)
constexpr size_t C32_SZ   = (size_t)BATCH * HDIM * 4;
constexpr size_t HP32_OFF = C32_OFF + C32_SZ;                    // f32 [B][512]     h@w_h2h.T + b (shared)
constexpr size_t HP32_SZ  = (size_t)BATCH * HDIM * 4;
constexpr size_t B2R_OFF  = HP32_OFF + HP32_SZ;                  // bf16 [2048][1024] gate-interleaved (RO)
constexpr size_t B2R_SZ   = (size_t)NG * 1024 * 2;
constexpr size_t WI2H_OFF = B2R_OFF + B2R_SZ;                    // bf16 [512][512] (RO)
constexpr size_t WI2H_SZ  = (size_t)HDIM * DIN * 2;
constexpr size_t B3_OFF   = WI2H_OFF + WI2H_SZ;                  // bf16 [576][512]  [w_h2h ; w_gen ; pad] (RO)
constexpr size_t B3_SZ    = (size_t)576 * HDIM * 2;
constexpr size_t WOH_OFF  = B3_OFF + B3_SZ;                      // f32 [2048][38] (RO)
constexpr size_t WOH_SZ   = (size_t)NG * NCLS * 4;
constexpr size_t BIAS_OFF = WOH_OFF + WOH_SZ;                    // f32 [2048] (RO)
constexpr size_t BIAS_SZ  = (size_t)NG * 4;
constexpr size_t HSEQ_OFF = BIAS_OFF + BIAS_SZ;                  // bf16 [S][B][512] (read post-decode only)
constexpr size_t HSEQ_SZ  = (size_t)STEPS * BATCH * HDIM * 2;
constexpr size_t BAR_OFF  = HSEQ_OFF + HSEQ_SZ;                  // u32 barrier state
constexpr size_t BAR_SZ   = 16384;

DEV float bf2f(unsigned short s) {
    unsigned u = ((unsigned)s) << 16;
    return __builtin_bit_cast(float, u);
}
DEV unsigned short f2bf(float f) {
    unsigned u = __builtin_bit_cast(unsigned, f);
    u = (u + 0x7fffu + ((u >> 16) & 1u)) >> 16;   // RNE
    return (unsigned short)u;
}
DEV float sigmoid_f(float x) { return 1.f / (1.f + __expf(-x)); }
DEV float tanh_f(float x) {
    x = fminf(fmaxf(x, -15.f), 15.f);
    float e = __expf(2.f * x);
    return (e - 1.f) / (e + 1.f);
}

DEV unsigned aload(const unsigned* p) {
    return __hip_atomic_load(p, __ATOMIC_RELAXED, __HIP_MEMORY_SCOPE_AGENT);
}
DEV float aloadf(const float* p) {
    return __hip_atomic_load(p, __ATOMIC_RELAXED, __HIP_MEMORY_SCOPE_AGENT);
}
DEV void astore(unsigned* p, unsigned v) {
    __hip_atomic_store(p, v, __ATOMIC_RELAXED, __HIP_MEMORY_SCOPE_AGENT);
}
DEV void astoref(float* p, float v) {
    __hip_atomic_store(p, v, __ATOMIC_RELAXED, __HIP_MEMORY_SCOPE_AGENT);
}

// ---------- fence-free grid barrier ----------
// All shared data moves through sc0/sc1 (MALL-coherent) atomics, so the
// barrier needs NO cache maintenance: __syncthreads() drains this block's
// stores (vmcnt 0) before arrival; flipper orders resets before gen-flip
// with an explicit vmcnt(0) wait.
// Layout (uints): 32 sub counters at i*32 (16 arrivals each), root at 1024,
// 32 gen replicas at 1056 + i*32.
DEV void gbar(unsigned* bar, int bid) {
    __syncthreads();                 // drains vmcnt(0): all stores visible at MALL
    if (threadIdx.x == 0) {
        const int sg = bid & 31;
        unsigned* sub  = bar + sg * 32;
        unsigned* root = bar + 1024;
        unsigned* genp = bar + 1056 + sg * 32;
        unsigned g = aload(genp);
        bool flipped = false;
        if (__hip_atomic_fetch_add(sub, 1u, __ATOMIC_RELAXED, __HIP_MEMORY_SCOPE_AGENT) == 15u) {
            if (__hip_atomic_fetch_add(root, 1u, __ATOMIC_RELAXED, __HIP_MEMORY_SCOPE_AGENT) == 31u) {
                #pragma unroll
                for (int i = 0; i < 32; i++) astore(bar + i * 32, 0u);
                astore(root, 0u);
                asm volatile("s_waitcnt vmcnt(0)" ::: "memory");   // resets land before flips
                #pragma unroll
                for (int i = 0; i < 32; i++) astore(bar + 1056 + i * 32, g + 1u);
                flipped = true;
            }
        }
        if (!flipped) {
            while (aload(genp) == g) __builtin_amdgcn_s_sleep(1);
        }
    }
    __syncthreads();
}

// ---------------- conversion / init kernels ----------------
__global__ void conv_bf16_kernel(const float* __restrict__ in,
                                 unsigned short* __restrict__ out, int n4) {
    int i = blockIdx.x * blockDim.x + threadIdx.x;
    int stride = gridDim.x * blockDim.x;
    for (; i < n4; i += stride) {
        float4 v = ((const float4*)in)[i];
        ushort4 o;
        o.x = f2bf(v.x); o.y = f2bf(v.y); o.z = f2bf(v.z); o.w = f2bf(v.w);
        ((ushort4*)out)[i] = o;
    }
}

__global__ void build_b2r_kernel(const float* __restrict__ w_ih, const float* __restrict__ w_hh,
                                 const float* __restrict__ b_ih, const float* __restrict__ b_hh,
                                 unsigned short* __restrict__ B2r, float* __restrict__ woh,
                                 float* __restrict__ bias2r) {
    int np = blockIdx.x;            // 0..2047 (n' = u*4+g)
    int u = np >> 2, g = np & 3;
    int src = g * 512 + u;
    for (int k = threadIdx.x; k < 512; k += blockDim.x) {
        B2r[np * 1024 + k]       = f2bf(w_ih[src * 550 + k]);
        B2r[np * 1024 + 512 + k] = f2bf(w_hh[src * 512 + k]);
    }
    if (threadIdx.x < NCLS) woh[np * NCLS + threadIdx.x] = w_ih[src * 550 + 512 + threadIdx.x];
    if (threadIdx.x == 0)   bias2r[np] = b_ih[src] + b_hh[src];
}

__global__ void build_b3_kernel(const float* __restrict__ w_h2h, const float* __restrict__ w_gen,
                                unsigned short* __restrict__ B3) {
    int n = blockIdx.x;             // 0..575
    for (int k = threadIdx.x; k < 512; k += blockDim.x) {
        float v = 0.f;
        if (n < 512)      v = w_h2h[n * 512 + k];
        else if (n < 550) v = w_gen[(n - 512) * 512 + k];
        B3[n * 512 + k] = f2bf(v);
    }
}

__global__ void init_state_kernel(float* __restrict__ c32, float* __restrict__ hp32,
                                  unsigned short* __restrict__ A2,
                                  const float* __restrict__ b_h2h,
                                  unsigned* __restrict__ bar) {
    int b = blockIdx.x;
    for (int j = threadIdx.x; j < 512; j += blockDim.x) {
        c32[b * 512 + j]  = 0.f;
        hp32[b * 512 + j] = b_h2h[j];          // h0 = 0 -> hp = b_h2h
        A2[b * 1024 + 512 + j] = 0;            // h part of buffer 0 = 0
    }
    if (b == 0)
        for (int j = threadIdx.x; j < 2112; j += blockDim.x) bar[j] = 0;
}

// ---------------- generic MFMA GEMM core ----------------
// C[m0:BM, n0:BN] += A * B^T ; A,B row-major bf16; waves (4/WN)xWN;
// wave tile (FRM*16)x(FRN*16); BK=32; LDS row stride 40 elems.
// COHA: stage A via agent-coherent (sc0/sc1) dword loads.
template<int BM, int BN, int WN, int FRM, int FRN, bool COHA = false>
DEV void gemm_core(const unsigned short* __restrict__ A, int ldA,
                   const unsigned short* __restrict__ Bm, int ldB, int K,
                   int m0, int n0, unsigned short* __restrict__ lA,
                   unsigned short* __restrict__ lB, f32x4 acc[FRM][FRN]) {
    constexpr int LSTR = 40;
    const int tid  = threadIdx.x;
    const int lane = tid & 63;
    const int wid  = tid >> 6;
    const int wm = wid / WN, wn = wid % WN;
    const int fr_row = lane & 15;
    const int fr_kb  = (lane >> 4) * 8;

    for (int k0 = 0; k0 < K; k0 += 32) {
        for (int u = tid; u < BM * 4; u += 256) {
            int r = u >> 2, cb = u & 3;
            if constexpr (COHA) {
                const unsigned* src = (const unsigned*)(A + (size_t)(m0 + r) * ldA + k0 + cb * 8);
                i32x4 v;
                v.x = (int)aload(src + 0);
                v.y = (int)aload(src + 1);
                v.z = (int)aload(src + 2);
                v.w = (int)aload(src + 3);
                *(i32x4*)(lA + r * LSTR + cb * 8) = v;
            } else {
                *(i32x4*)(lA + r * LSTR + cb * 8) =
                    *(const i32x4*)(A + (size_t)(m0 + r) * ldA + k0 + cb * 8);
            }
        }
        for (int u = tid; u < BN * 4; u += 256) {
            int r = u >> 2, cb = u & 3;
            *(i32x4*)(lB + r * LSTR + cb * 8) =
                *(const i32x4*)(Bm + (size_t)(n0 + r) * ldB + k0 + cb * 8);
        }
        __syncthreads();
        bf16x8 af[FRM], bfv[FRN];
        #pragma unroll
        for (int i = 0; i < FRM; i++)
            af[i] = *(const bf16x8*)(lA + (wm * FRM * 16 + i * 16 + fr_row) * LSTR + fr_kb);
        #pragma unroll
        for (int j = 0; j < FRN; j++)
            bfv[j] = *(const bf16x8*)(lB + (wn * FRN * 16 + j * 16 + fr_row) * LSTR + fr_kb);
        #pragma unroll
        for (int i = 0; i < FRM; i++)
            #pragma unroll
            for (int j = 0; j < FRN; j++)
                acc[i][j] = __builtin_amdgcn_mfma_f32_16x16x32_bf16(af[i], bfv[j], acc[i][j], 0, 0, 0);
        __syncthreads();
    }
}

// ---------------- H_proj GEMM (bf16 output) ----------------
__global__ __launch_bounds__(256) void gemm_bf16out_kernel(
    const unsigned short* __restrict__ A, int ldA,
    const unsigned short* __restrict__ Bm, int ldB,
    unsigned short* __restrict__ C, int ldC, int K) {
    constexpr int BM = 128, BN = 128, FRM = 4, FRN = 4;
    __shared__ __align__(16) unsigned short lA[BM * 40], lB[BN * 40];
    int m0 = blockIdx.x * BM, n0 = blockIdx.y * BN;
    f32x4 acc[FRM][FRN] = {};
    gemm_core<BM, BN, 2, FRM, FRN>(A, ldA, Bm, ldB, K, m0, n0, lA, lB, acc);
    const int lane = threadIdx.x & 63, wid = threadIdx.x >> 6;
    const int wm = wid >> 1, wn = wid & 1;
    #pragma unroll
    for (int i = 0; i < FRM; i++)
        #pragma unroll
        for (int j = 0; j < FRN; j++)
            #pragma unroll
            for (int r = 0; r < 4; r++) {
                int m = m0 + wm * FRM * 16 + i * 16 + (lane >> 4) * 4 + r;
                int n = n0 + wn * FRN * 16 + j * 16 + (lane & 15);
                C[(size_t)m * ldC + n] = f2bf(acc[i][j][r]);
            }
}

// ---------------- final probs GEMM ----------------
__global__ __launch_bounds__(256) void probs_kernel(
    const unsigned short* __restrict__ hseq,   // [S*B][512] bf16
    const unsigned short* __restrict__ Bg,     // [64][512]  bf16 (w_gen padded)
    const float* __restrict__ b_gen, float* __restrict__ out) {
    __shared__ __align__(16) unsigned short lA[64 * 40], lB[64 * 40];
    int m0 = blockIdx.x * 64;
    f32x4 acc[2][2] = {};
    gemm_core<64, 64, 2, 2, 2>(hseq, 512, Bg, 512, 512, m0, 0, lA, lB, acc);
    const int lane = threadIdx.x & 63, wid = threadIdx.x >> 6;
    const int wm = wid >> 1, wn = wid & 1;
    #pragma unroll
    for (int i = 0; i < 2; i++)
        #pragma unroll
        for (int j = 0; j < 2; j++)
            #pragma unroll
            for (int r = 0; r < 4; r++) {
                int m = m0 + wm * 32 + i * 16 + (lane >> 4) * 4 + r;
                int n = wn * 32 + j * 16 + (lane & 15);
                if (n < NCLS) {
                    int ss = m >> 9, b = m & 511;   // hseq row = s*512 + b
                    out[((size_t)b * STEPS + ss) * NCLS + n] = acc[i][j][r] + b_gen[n];
                }
            }
}

// ---------------- cooperative decode kernel: all 26 steps ----------------
__global__ __launch_bounds__(256, 2) void decode_kernel(
    const unsigned short* __restrict__ Hp,
    const unsigned short* __restrict__ enc,
    unsigned short* __restrict__ A2,       // [2][B][1024]
    float* __restrict__ c32,
    float* __restrict__ hp32,
    const unsigned short* __restrict__ B2r,
    const float* __restrict__ bias2r,
    const float* __restrict__ woh,
    const unsigned short* __restrict__ B3,
    const float* __restrict__ b_h2h,
    const float* __restrict__ w_score,
    const int* __restrict__ text,
    unsigned short* __restrict__ hseq,
    unsigned* __restrict__ bar) {
    __shared__ __align__(16) char smem[17920];
    const int bid  = blockIdx.x;
    const int tid  = threadIdx.x;
    const int lane = tid & 63, wid = tid >> 6;

    for (int s = 0; s < STEPS; ++s) {
        unsigned short* A2cur = A2 + (size_t)(s & 1) * BATCH * 1024;
        unsigned short* A2nxt = A2 + (size_t)((s + 1) & 1) * BATCH * 1024;

        // ---- phase 1: attention; block = batch row ----
        {
            float* e_lds = (float*)smem;
            float* alpha_lds = e_lds + 64;
            const int b = bid;
            float hp8[8], ws8[8];
            {
                const float* hpr = hp32 + b * 512 + lane * 8;
                #pragma unroll
                for (int j = 0; j < 8; j++) hp8[j] = aloadf(hpr + j);   // coherent: written by phase 3
                const float4* ws4 = (const float4*)(w_score + lane * 8);
                float4 w0 = ws4[0], w1 = ws4[1];
                ws8[0] = w0.x; ws8[1] = w0.y; ws8[2] = w0.z; ws8[3] = w0.w;
                ws8[4] = w1.x; ws8[5] = w1.y; ws8[6] = w1.z; ws8[7] = w1.w;
            }
            for (int t = wid; t < 64; t += 4) {
                bf16x8 hv = *(const bf16x8*)(Hp + ((size_t)b * 64 + t) * 512 + lane * 8);
                float a = 0.f;
                #pragma unroll
                for (int j = 0; j < 8; j++)
                    a += ws8[j] * tanh_f(hp8[j] + bf2f((unsigned short)hv[j]));
                #pragma unroll
                for (int off = 32; off > 0; off >>= 1) a += __shfl_down(a, off);
                if (lane == 0) e_lds[t] = a;
            }
            __syncthreads();
            if (wid == 0) {
                float v = e_lds[lane];
                float m = v;
                #pragma unroll
                for (int off = 32; off > 0; off >>= 1) m = fmaxf(m, __shfl_xor(m, off));
                float ex = __expf(v - m);
                float sum = ex;
                #pragma unroll
                for (int off = 32; off > 0; off >>= 1) sum += __shfl_xor(sum, off);
                alpha_lds[lane] = ex / sum;
            }
            __syncthreads();
            float a0 = 0.f, a1 = 0.f;
            const unsigned short* erow = enc + (size_t)b * 64 * 512 + tid * 2;
            #pragma unroll 8
            for (int t = 0; t < 64; t++) {
                float al = alpha_lds[t];
                unsigned pv = *(const unsigned*)(erow + (size_t)t * 512);
                a0 += al * bf2f((unsigned short)(pv & 0xffffu));
                a1 += al * bf2f((unsigned short)(pv >> 16));
            }
            unsigned pk = ((unsigned)f2bf(a1) << 16) | (unsigned)f2bf(a0);
            astore((unsigned*)(A2cur + (size_t)b * 1024) + tid, pk);    // coherent ctx
        }
        gbar(bar, bid);

        // ---- phase 2: gates GEMM + LSTM pointwise; 512 blocks, 32x64 tiles ----
        {
            unsigned short* lA = (unsigned short*)smem;          // 32*40*2 = 2560 B
            unsigned short* lB = lA + 32 * 40;                   // 64*40*2 = 5120 B
            float* gbuf = (float*)(smem + 7680);                 // [32][68] = 8704 B
            const int m0 = (bid >> 5) * 32, n0 = (bid & 31) * 64;
            f32x4 acc[1][2] = {};
            gemm_core<32, 64, 2, 1, 2, true>(A2cur, 1024, B2r, 1024, 1024, m0, n0, lA, lB, acc);
            const int wm = wid >> 1, wn = wid & 1;
            #pragma unroll
            for (int j = 0; j < 2; j++)
                #pragma unroll
                for (int r = 0; r < 4; r++) {
                    int ml = wm * 16 + (lane >> 4) * 4 + r;
                    int nl = wn * 32 + j * 16 + (lane & 15);
                    gbuf[ml * 68 + nl] = acc[0][j][r];
                }
            __syncthreads();
            {   // one iteration per thread: (row, unit-pair)
                int rl = tid >> 3, q = tid & 7;
                int b  = m0 + rl;
                int nb = n0 + q * 8;         // 8 gate slots = 2 units
                int u  = nb >> 2;
                int tb = text[b * STEPS + s];
                const float* gr = gbuf + rl * 68 + q * 8;
                float4 g0 = *(const float4*)(gr);
                float4 g1 = *(const float4*)(gr + 4);
                float vi0 = g0.x + bias2r[nb + 0] + woh[(nb + 0) * NCLS + tb];
                float vf0 = g0.y + bias2r[nb + 1] + woh[(nb + 1) * NCLS + tb];
                float vg0 = g0.z + bias2r[nb + 2] + woh[(nb + 2) * NCLS + tb];
                float vo0 = g0.w + bias2r[nb + 3] + woh[(nb + 3) * NCLS + tb];
                float vi1 = g1.x + bias2r[nb + 4] + woh[(nb + 4) * NCLS + tb];
                float vf1 = g1.y + bias2r[nb + 5] + woh[(nb + 5) * NCLS + tb];
                float vg1 = g1.z + bias2r[nb + 6] + woh[(nb + 6) * NCLS + tb];
                float vo1 = g1.w + bias2r[nb + 7] + woh[(nb + 7) * NCLS + tb];
                float c0 = c32[b * 512 + u], c1 = c32[b * 512 + u + 1];   // block-local
                float cn0 = sigmoid_f(vf0) * c0 + sigmoid_f(vi0) * tanh_f(vg0);
                float cn1 = sigmoid_f(vf1) * c1 + sigmoid_f(vi1) * tanh_f(vg1);
                float hn0 = sigmoid_f(vo0) * tanh_f(cn0);
                float hn1 = sigmoid_f(vo1) * tanh_f(cn1);
                c32[b * 512 + u] = cn0;
                c32[b * 512 + u + 1] = cn1;
                unsigned hp2 = ((unsigned)f2bf(hn1) << 16) | (unsigned)f2bf(hn0);
                astore((unsigned*)(A2nxt + (size_t)b * 1024 + 512 + u), hp2);  // coherent h
                *(unsigned*)(hseq + ((size_t)s * BATCH + b) * 512 + u) = hp2;  // post-kernel only
            }
        }

        // ---- phase 3: hp = h_new @ w_h2h^T + b_h2h (skipped on last step) ----
        if (s + 1 < STEPS) {
            gbar(bar, bid);
            if (bid < 256) {
                unsigned short* lA = (unsigned short*)smem;
                unsigned short* lB = lA + 32 * 40;
                const int m0 = (bid >> 4) * 32, n0 = (bid & 15) * 32;
                f32x4 acc[1][1] = {};
                gemm_core<32, 32, 2, 1, 1, true>(A2nxt + 512, 1024, B3, 512, 512, m0, n0, lA, lB, acc);
                const int wm = wid >> 1, wn = wid & 1;
                #pragma unroll
                for (int r = 0; r < 4; r++) {
                    int m = m0 + wm * 16 + (lane >> 4) * 4 + r;
                    int n = n0 + wn * 16 + (lane & 15);
                    astoref(hp32 + m * 512 + n, acc[0][0][r] + b_h2h[n]);   // coherent hp
                }
            }
            gbar(bar, bid);
        }
    }
}

// ---------------- host ----------------
extern "C" void kernel_launch(void* const* d_in, const int* in_sizes, int n_in,
                              void* d_out, int out_size, void* d_ws, size_t ws_size,
                              hipStream_t stream) {
    (void)in_sizes; (void)n_in; (void)out_size; (void)ws_size;
    const float* enc_f   = (const float*)d_in[0];
    const int*   text    = (const int*)d_in[1];
    const float* w_i2h   = (const float*)d_in[2];
    const float* w_h2h   = (const float*)d_in[3];
    const float* b_h2h   = (const float*)d_in[4];
    const float* w_score = (const float*)d_in[5];
    const float* w_ih    = (const float*)d_in[6];
    const float* w_hh    = (const float*)d_in[7];
    const float* b_ih    = (const float*)d_in[8];
    const float* b_hh    = (const float*)d_in[9];
    const float* w_gen   = (const float*)d_in[10];
    const float* b_gen   = (const float*)d_in[11];
    float* out = (float*)d_out;

    char* ws = (char*)d_ws;
    const unsigned short* Hp     = (const unsigned short*)(ws + HP_OFF);
    unsigned short*       Hp_w   = (unsigned short*)(ws + HP_OFF);
    const unsigned short* encb   = (const unsigned short*)(ws + ENC_OFF);
    unsigned short*       encb_w = (unsigned short*)(ws + ENC_OFF);
    unsigned short*       A2     = (unsigned short*)(ws + A2_OFF);
    float*                c32    = (float*)(ws + C32_OFF);
    float*                hp32   = (float*)(ws + HP32_OFF);
    const unsigned short* B2r    = (const unsigned short*)(ws + B2R_OFF);
    unsigned short*       B2r_w  = (unsigned short*)(ws + B2R_OFF);
    unsigned short*       wi2hb  = (unsigned short*)(ws + WI2H_OFF);
    const unsigned short* B3     = (const unsigned short*)(ws + B3_OFF);
    unsigned short*       B3_w   = (unsigned short*)(ws + B3_OFF);
    const float*          woh    = (const float*)(ws + WOH_OFF);
    float*                woh_w  = (float*)(ws + WOH_OFF);
    const float*          bias2r = (const float*)(ws + BIAS_OFF);
    float*                bias2r_w = (float*)(ws + BIAS_OFF);
    unsigned short*       hseq   = (unsigned short*)(ws + HSEQ_OFF);
    unsigned*             bar    = (unsigned*)(ws + BAR_OFF);

    conv_bf16_kernel<<<2048, 256, 0, stream>>>(enc_f, encb_w, BATCH * TENC * DIN / 4);
    conv_bf16_kernel<<<256, 256, 0, stream>>>(w_i2h, wi2hb, HDIM * DIN / 4);
    build_b2r_kernel<<<NG, 256, 0, stream>>>(w_ih, w_hh, b_ih, b_hh, B2r_w, woh_w, bias2r_w);
    build_b3_kernel<<<576, 256, 0, stream>>>(w_h2h, w_gen, B3_w);
    init_state_kernel<<<BATCH, 256, 0, stream>>>(c32, hp32, A2, b_h2h, bar);

    // H_proj = enc @ w_i2h^T  (M=32768, N=512, K=512)
    gemm_bf16out_kernel<<<dim3(BATCH * TENC / 128, HDIM / 128), 256, 0, stream>>>(
        encb, DIN, wi2hb, DIN, Hp_w, HDIM, DIN);

    // cooperative decode: all 26 steps in one launch (fence-free barrier inside)
    {
        void* args[14] = {
            (void*)&Hp, (void*)&encb, (void*)&A2, (void*)&c32, (void*)&hp32,
            (void*)&B2r, (void*)&bias2r, (void*)&woh, (void*)&B3,
            (void*)&b_h2h, (void*)&w_score, (void*)&text, (void*)&hseq, (void*)&bar
        };
        hipLaunchCooperativeKernel((const void*)decode_kernel, dim3(512), dim3(256),
                                   args, 0, stream);
    }

    // probs = hseq @ [w_gen;0]^T + b_gen  (M = S*B = 13312, N = 64, K = 512)
    probs_kernel<<<dim3(STEPS * BATCH / 64), 256, 0, stream>>>(
        hseq, B3 + (size_t)512 * 512, b_gen, out);
}

// Round 8
// 1358.232 us; speedup vs baseline: 4.1704x; 1.2627x over previous
//
#include <hip/hip_runtime.h>

typedef __attribute__((ext_vector_type(8))) short bf16x8;
typedef __attribute__((ext_vector_type(4))) float f32x4;
typedef __attribute__((ext_vector_type(4))) int   i32x4;

#define DEV static __device__ __forceinline__

constexpr int BATCH = 512;
constexpr int TENC  = 64;
constexpr int DIN   = 512;
constexpr int HDIM  = 512;
constexpr int NCLS  = 38;
constexpr int STEPS = 26;
constexpr int NG    = 4 * HDIM;   // 2048

// ---- workspace layout (bytes) ----
constexpr size_t HP_OFF   = 0;                                   // bf16 [B*T][512]  H_proj
constexpr size_t HP_SZ    = (size_t)BATCH * TENC * HDIM * 2;
constexpr size_t ENC_OFF  = HP_OFF + HP_SZ;                      // bf16 [B*T][512]  encoder
constexpr size_t ENC_SZ   = (size_t)BATCH * TENC * DIN * 2;
constexpr size_t A2_OFF   = ENC_OFF + ENC_SZ;                    // bf16 [2][B][1024] ping-pong [ctx | h]
constexpr size_t A2_SZ    = (size_t)2 * BATCH * 1024 * 2;
constexpr size_t HP32_OFF = A2_OFF + A2_SZ;                      // f32 [B][512]  h@w_h2h.T + b (shared)
constexpr size_t HP32_SZ  = (size_t)BATCH * HDIM * 4;
constexpr size_t B2R_OFF  = HP32_OFF + HP32_SZ;                  // bf16 [2048][1024] gate-interleaved (RO)
constexpr size_t B2R_SZ   = (size_t)NG * 1024 * 2;
constexpr size_t WI2H_OFF = B2R_OFF + B2R_SZ;                    // bf16 [512][512] (RO)
constexpr size_t WI2H_SZ  = (size_t)HDIM * DIN * 2;
constexpr size_t B3_OFF   = WI2H_OFF + WI2H_SZ;                  // bf16 [576][512]  [w_h2h ; w_gen ; pad] (RO)
constexpr size_t B3_SZ    = (size_t)576 * HDIM * 2;
constexpr size_t WOH_OFF  = B3_OFF + B3_SZ;                      // f32 [2048][38] (RO)
constexpr size_t WOH_SZ   = (size_t)NG * NCLS * 4;
constexpr size_t BIAS_OFF = WOH_OFF + WOH_SZ;                    // f32 [2048] (RO)
constexpr size_t BIAS_SZ  = (size_t)NG * 4;
constexpr size_t HSEQ_OFF = BIAS_OFF + BIAS_SZ;                  // bf16 [S][B][512] (read post-decode only)
constexpr size_t HSEQ_SZ  = (size_t)STEPS * BATCH * HDIM * 2;
constexpr size_t BAR_OFF  = HSEQ_OFF + HSEQ_SZ;                  // u32 barrier state
constexpr size_t BAR_SZ   = 16384;

DEV float bf2f(unsigned short s) {
    unsigned u = ((unsigned)s) << 16;
    return __builtin_bit_cast(float, u);
}
DEV unsigned short f2bf(float f) {
    unsigned u = __builtin_bit_cast(unsigned, f);
    u = (u + 0x7fffu + ((u >> 16) & 1u)) >> 16;   // RNE
    return (unsigned short)u;
}
DEV float sigmoid_f(float x) { return 1.f / (1.f + __expf(-x)); }
DEV float tanh_f(float x) {
    x = fminf(fmaxf(x, -15.f), 15.f);
    float e = __expf(2.f * x);
    return (e - 1.f) / (e + 1.f);
}

DEV unsigned aload(const unsigned* p) {
    return __hip_atomic_load(p, __ATOMIC_RELAXED, __HIP_MEMORY_SCOPE_AGENT);
}
DEV unsigned long long aload64(const unsigned long long* p) {
    return __hip_atomic_load(p, __ATOMIC_RELAXED, __HIP_MEMORY_SCOPE_AGENT);
}
DEV float aloadf(const float* p) {
    return __hip_atomic_load(p, __ATOMIC_RELAXED, __HIP_MEMORY_SCOPE_AGENT);
}
DEV void astore(unsigned* p, unsigned v) {
    __hip_atomic_store(p, v, __ATOMIC_RELAXED, __HIP_MEMORY_SCOPE_AGENT);
}
DEV void astoref(float* p, float v) {
    __hip_atomic_store(p, v, __ATOMIC_RELAXED, __HIP_MEMORY_SCOPE_AGENT);
}
DEV bf16x8 mk_frag(unsigned long long lo, unsigned long long hi) {
    union { unsigned long long q[2]; bf16x8 v; } u;
    u.q[0] = lo; u.q[1] = hi;
    return u.v;
}

// ---------- fence-free grid barrier (256 blocks: 32 subgroups x 8) ----------
DEV void gbar(unsigned* bar, int bid) {
    __syncthreads();                 // drains this block's stores (vmcnt 0)
    if (threadIdx.x == 0) {
        const int sg = bid & 31;
        unsigned* sub  = bar + sg * 32;
        unsigned* root = bar + 1024;
        unsigned* genp = bar + 1056 + sg * 32;
        unsigned g = aload(genp);
        bool flipped = false;
        if (__hip_atomic_fetch_add(sub, 1u, __ATOMIC_RELAXED, __HIP_MEMORY_SCOPE_AGENT) == 7u) {
            if (__hip_atomic_fetch_add(root, 1u, __ATOMIC_RELAXED, __HIP_MEMORY_SCOPE_AGENT) == 31u) {
                #pragma unroll
                for (int i = 0; i < 32; i++) astore(bar + i * 32, 0u);
                astore(root, 0u);
                asm volatile("s_waitcnt vmcnt(0)" ::: "memory");   // resets land before flips
                #pragma unroll
                for (int i = 0; i < 32; i++) astore(bar + 1056 + i * 32, g + 1u);
                flipped = true;
            }
        }
        if (!flipped) {
            while (aload(genp) == g) __builtin_amdgcn_s_sleep(1);
        }
    }
    __syncthreads();
}

// ---------------- conversion / init kernels ----------------
__global__ void conv_bf16_kernel(const float* __restrict__ in,
                                 unsigned short* __restrict__ out, int n4) {
    int i = blockIdx.x * blockDim.x + threadIdx.x;
    int stride = gridDim.x * blockDim.x;
    for (; i < n4; i += stride) {
        float4 v = ((const float4*)in)[i];
        ushort4 o;
        o.x = f2bf(v.x); o.y = f2bf(v.y); o.z = f2bf(v.z); o.w = f2bf(v.w);
        ((ushort4*)out)[i] = o;
    }
}

__global__ void build_b2r_kernel(const float* __restrict__ w_ih, const float* __restrict__ w_hh,
                                 const float* __restrict__ b_ih, const float* __restrict__ b_hh,
                                 unsigned short* __restrict__ B2r, float* __restrict__ woh,
                                 float* __restrict__ bias2r) {
    int np = blockIdx.x;            // 0..2047 (n' = u*4+g)
    int u = np >> 2, g = np & 3;
    int src = g * 512 + u;
    for (int k = threadIdx.x; k < 512; k += blockDim.x) {
        B2r[np * 1024 + k]       = f2bf(w_ih[src * 550 + k]);
        B2r[np * 1024 + 512 + k] = f2bf(w_hh[src * 512 + k]);
    }
    if (threadIdx.x < NCLS) woh[np * NCLS + threadIdx.x] = w_ih[src * 550 + 512 + threadIdx.x];
    if (threadIdx.x == 0)   bias2r[np] = b_ih[src] + b_hh[src];
}

__global__ void build_b3_kernel(const float* __restrict__ w_h2h, const float* __restrict__ w_gen,
                                unsigned short* __restrict__ B3) {
    int n = blockIdx.x;             // 0..575
    for (int k = threadIdx.x; k < 512; k += blockDim.x) {
        float v = 0.f;
        if (n < 512)      v = w_h2h[n * 512 + k];
        else if (n < 550) v = w_gen[(n - 512) * 512 + k];
        B3[n * 512 + k] = f2bf(v);
    }
}

__global__ void init_state_kernel(float* __restrict__ hp32,
                                  unsigned short* __restrict__ A2,
                                  const float* __restrict__ b_h2h,
                                  unsigned* __restrict__ bar) {
    int b = blockIdx.x;
    for (int j = threadIdx.x; j < 512; j += blockDim.x) {
        hp32[b * 512 + j] = b_h2h[j];          // h0 = 0 -> hp = b_h2h
        A2[b * 1024 + 512 + j] = 0;            // h part of buffer 0 = 0
    }
    if (b == 0)
        for (int j = threadIdx.x; j < 2112; j += blockDim.x) bar[j] = 0;
}

// ---------------- generic MFMA GEMM core (used by H_proj / probs) ----------------
template<int BM, int BN, int WN, int FRM, int FRN>
DEV void gemm_core(const unsigned short* __restrict__ A, int ldA,
                   const unsigned short* __restrict__ Bm, int ldB, int K,
                   int m0, int n0, unsigned short* __restrict__ lA,
                   unsigned short* __restrict__ lB, f32x4 acc[FRM][FRN]) {
    constexpr int LSTR = 40;
    const int tid  = threadIdx.x;
    const int lane = tid & 63;
    const int wid  = tid >> 6;
    const int wm = wid / WN, wn = wid % WN;
    const int fr_row = lane & 15;
    const int fr_kb  = (lane >> 4) * 8;

    for (int k0 = 0; k0 < K; k0 += 32) {
        for (int u = tid; u < BM * 4; u += 256) {
            int r = u >> 2, cb = u & 3;
            *(i32x4*)(lA + r * LSTR + cb * 8) =
                *(const i32x4*)(A + (size_t)(m0 + r) * ldA + k0 + cb * 8);
        }
        for (int u = tid; u < BN * 4; u += 256) {
            int r = u >> 2, cb = u & 3;
            *(i32x4*)(lB + r * LSTR + cb * 8) =
                *(const i32x4*)(Bm + (size_t)(n0 + r) * ldB + k0 + cb * 8);
        }
        __syncthreads();
        bf16x8 af[FRM], bfv[FRN];
        #pragma unroll
        for (int i = 0; i < FRM; i++)
            af[i] = *(const bf16x8*)(lA + (wm * FRM * 16 + i * 16 + fr_row) * LSTR + fr_kb);
        #pragma unroll
        for (int j = 0; j < FRN; j++)
            bfv[j] = *(const bf16x8*)(lB + (wn * FRN * 16 + j * 16 + fr_row) * LSTR + fr_kb);
        #pragma unroll
        for (int i = 0; i < FRM; i++)
            #pragma unroll
            for (int j = 0; j < FRN; j++)
                acc[i][j] = __builtin_amdgcn_mfma_f32_16x16x32_bf16(af[i], bfv[j], acc[i][j], 0, 0, 0);
        __syncthreads();
    }
}

// ---------------- H_proj GEMM (bf16 output) ----------------
__global__ __launch_bounds__(256) void gemm_bf16out_kernel(
    const unsigned short* __restrict__ A, int ldA,
    const unsigned short* __restrict__ Bm, int ldB,
    unsigned short* __restrict__ C, int ldC, int K) {
    constexpr int BM = 128, BN = 128, FRM = 4, FRN = 4;
    __shared__ __align__(16) unsigned short lA[BM * 40], lB[BN * 40];
    int m0 = blockIdx.x * BM, n0 = blockIdx.y * BN;
    f32x4 acc[FRM][FRN] = {};
    gemm_core<BM, BN, 2, FRM, FRN>(A, ldA, Bm, ldB, K, m0, n0, lA, lB, acc);
    const int lane = threadIdx.x & 63, wid = threadIdx.x >> 6;
    const int wm = wid >> 1, wn = wid & 1;
    #pragma unroll
    for (int i = 0; i < FRM; i++)
        #pragma unroll
        for (int j = 0; j < FRN; j++)
            #pragma unroll
            for (int r = 0; r < 4; r++) {
                int m = m0 + wm * FRM * 16 + i * 16 + (lane >> 4) * 4 + r;
                int n = n0 + wn * FRN * 16 + j * 16 + (lane & 15);
                C[(size_t)m * ldC + n] = f2bf(acc[i][j][r]);
            }
}

// ---------------- final probs GEMM ----------------
__global__ __launch_bounds__(256) void probs_kernel(
    const unsigned short* __restrict__ hseq,   // [S*B][512] bf16
    const unsigned short* __restrict__ Bg,     // [64][512]  bf16 (w_gen padded)
    const float* __restrict__ b_gen, float* __restrict__ out) {
    __shared__ __align__(16) unsigned short lA[64 * 40], lB[64 * 40];
    int m0 = blockIdx.x * 64;
    f32x4 acc[2][2] = {};
    gemm_core<64, 64, 2, 2, 2>(hseq, 512, Bg, 512, 512, m0, 0, lA, lB, acc);
    const int lane = threadIdx.x & 63, wid = threadIdx.x >> 6;
    const int wm = wid >> 1, wn = wid & 1;
    #pragma unroll
    for (int i = 0; i < 2; i++)
        #pragma unroll
        for (int j = 0; j < 2; j++)
            #pragma unroll
            for (int r = 0; r < 4; r++) {
                int m = m0 + wm * 32 + i * 16 + (lane >> 4) * 4 + r;
                int n = wn * 32 + j * 16 + (lane & 15);
                if (n < NCLS) {
                    int ss = m >> 9, b = m & 511;   // hseq row = s*512 + b
                    out[((size_t)b * STEPS + ss) * NCLS + n] = acc[i][j][r] + b_gen[n];
                }
            }
}

// ---------------- cooperative decode: 256 blocks x 512 threads, 1 block/CU ----------------
// Persistent LDS: gates B-slice [32][1024] (pad->1032) + hp B-slice [32][512] (pad->520).
// Activations read via agent-coherent u64 loads (batched, register-resident fragments).
// Cell state lives in 2 registers/thread (thread<->unit mapping is step-invariant).
__global__ __launch_bounds__(512, 2) void decode_kernel(
    const unsigned short* __restrict__ Hp,
    const unsigned short* __restrict__ enc,
    unsigned short* __restrict__ A2,       // [2][B][1024]
    float* __restrict__ hp32,
    const unsigned short* __restrict__ B2r,
    const float* __restrict__ bias2r,
    const float* __restrict__ woh,
    const unsigned short* __restrict__ B3,
    const float* __restrict__ b_h2h,
    const float* __restrict__ w_score,
    const int* __restrict__ text,
    unsigned short* __restrict__ hseq,
    unsigned* __restrict__ bar) {
    __shared__ __align__(16) unsigned short lB2[32 * 1032];   // 66048 B
    __shared__ __align__(16) unsigned short lB3[32 * 520];    // 33280 B
    __shared__ __align__(16) char scr[18432];                 // attn e/alpha | gbuf | pbuf

    const int bid  = blockIdx.x;
    const int tid  = threadIdx.x;
    const int lane = tid & 63, wid = tid >> 6;

    const int nb = bid & 63;          // gates n-chunk (32 cols)
    const int mb = bid >> 6;          // gates m-chunk (128 rows)
    const int n3 = bid & 15;          // hp n-chunk (32 cols)
    const int m3 = bid >> 4;          // hp m-chunk (32 rows)

    // ---- one-time persistent weight preload ----
    for (int u = tid; u < 4096; u += 512) {       // 32 rows x 128 chunks of 8 elems
        int r = u >> 7, cb = u & 127;
        *(i32x4*)(lB2 + r * 1032 + cb * 8) =
            *(const i32x4*)(B2r + (size_t)(nb * 32 + r) * 1024 + cb * 8);
    }
    for (int u = tid; u < 2048; u += 512) {       // 32 rows x 64 chunks
        int r = u >> 6, cb = u & 63;
        *(i32x4*)(lB3 + r * 520 + cb * 8) =
            *(const i32x4*)(B3 + (size_t)(n3 * 32 + r) * 512 + cb * 8);
    }

    float c0 = 0.f, c1 = 0.f;   // persistent cell state: this thread's 2 units

    for (int s = 0; s < STEPS; ++s) {
        unsigned short* A2cur = A2 + (size_t)(s & 1) * BATCH * 1024;
        unsigned short* A2nxt = A2 + (size_t)((s + 1) & 1) * BATCH * 1024;

        // ---- phase 1: attention; 2 batch rows per block ----
        {
            float* e_lds  = (float*)scr;          // [2][64]
            float* al_lds = e_lds + 128;          // [2][64]
            const int half = tid >> 8, t4 = tid & 255, w4 = t4 >> 6;
            const int b = bid * 2 + half;
            float hp8[8], ws8[8];
            const float* hpr = hp32 + b * 512 + lane * 8;
            #pragma unroll
            for (int j = 0; j < 8; j++) hp8[j] = aloadf(hpr + j);   // coherent (phase-3 output)
            {
                const float4* wsp = (const float4*)(w_score + lane * 8);
                float4 w0 = wsp[0], w1 = wsp[1];
                ws8[0] = w0.x; ws8[1] = w0.y; ws8[2] = w0.z; ws8[3] = w0.w;
                ws8[4] = w1.x; ws8[5] = w1.y; ws8[6] = w1.z; ws8[7] = w1.w;
            }
            for (int t = w4; t < 64; t += 4) {
                bf16x8 hv = *(const bf16x8*)(Hp + ((size_t)b * 64 + t) * 512 + lane * 8);
                float a = 0.f;
                #pragma unroll
                for (int j = 0; j < 8; j++)
                    a += ws8[j] * tanh_f(hp8[j] + bf2f((unsigned short)hv[j]));
                #pragma unroll
                for (int off = 32; off > 0; off >>= 1) a += __shfl_down(a, off);
                if (lane == 0) e_lds[half * 64 + t] = a;
            }
            __syncthreads();
            if (w4 == 0) {   // one wave per batch row does the softmax
                float v = e_lds[half * 64 + lane];
                float m = v;
                #pragma unroll
                for (int off = 32; off > 0; off >>= 1) m = fmaxf(m, __shfl_xor(m, off));
                float ex = __expf(v - m);
                float sum = ex;
                #pragma unroll
                for (int off = 32; off > 0; off >>= 1) sum += __shfl_xor(sum, off);
                al_lds[half * 64 + lane] = ex / sum;
            }
            __syncthreads();
            float a0 = 0.f, a1 = 0.f;
            const unsigned short* erow = enc + (size_t)b * 64 * 512 + t4 * 2;
            #pragma unroll 8
            for (int t = 0; t < 64; t++) {
                float al = al_lds[half * 64 + t];
                unsigned pv = *(const unsigned*)(erow + (size_t)t * 512);
                a0 += al * bf2f((unsigned short)(pv & 0xffffu));
                a1 += al * bf2f((unsigned short)(pv >> 16));
            }
            unsigned pk = ((unsigned)f2bf(a1) << 16) | (unsigned)f2bf(a0);
            astore((unsigned*)(A2cur + (size_t)b * 1024) + t4, pk);    // coherent ctx
        }
        gbar(bar, bid);

        // ---- phase 2: gates GEMM 128x32 (K=1024, B resident in LDS) + fused LSTM ----
        {
            const int m0 = mb * 128;
            const unsigned long long* Ab = (const unsigned long long*)
                (A2cur + (size_t)(m0 + wid * 16 + (lane & 15)) * 1024 + (lane >> 4) * 8);
            const unsigned short* lb0 = lB2 + (lane & 15) * 1032 + (lane >> 4) * 8;
            const unsigned short* lb1 = lb0 + 16 * 1032;
            f32x4 acc0 = {}, acc1 = {};
            #pragma unroll
            for (int hf = 0; hf < 2; ++hf) {
                unsigned long long a0v[16], a1v[16];
                #pragma unroll
                for (int kc = 0; kc < 16; ++kc) {        // batched coherent loads (pipelined)
                    a0v[kc] = aload64(Ab + (hf * 16 + kc) * 8);
                    a1v[kc] = aload64(Ab + (hf * 16 + kc) * 8 + 1);
                }
                #pragma unroll
                for (int kc = 0; kc < 16; ++kc) {
                    bf16x8 af = mk_frag(a0v[kc], a1v[kc]);
                    bf16x8 b0 = *(const bf16x8*)(lb0 + (hf * 16 + kc) * 32);
                    bf16x8 b1 = *(const bf16x8*)(lb1 + (hf * 16 + kc) * 32);
                    acc0 = __builtin_amdgcn_mfma_f32_16x16x32_bf16(af, b0, acc0, 0, 0, 0);
                    acc1 = __builtin_amdgcn_mfma_f32_16x16x32_bf16(af, b1, acc1, 0, 0, 0);
                }
            }
            float* gbuf = (float*)scr;   // [128][36]
            const int grow = wid * 16 + (lane >> 4) * 4;
            const int gcol = lane & 15;
            #pragma unroll
            for (int r = 0; r < 4; r++) {
                gbuf[(grow + r) * 36 + gcol]      = acc0[r];
                gbuf[(grow + r) * 36 + 16 + gcol] = acc1[r];
            }
            __syncthreads();
            {   // LSTM pointwise: thread -> (row, unit pair); c kept in registers
                const int rl = tid >> 2, q = tid & 3;
                const int b = m0 + rl;
                const int npb = nb * 32 + q * 8;       // global gate-slot base (2 units)
                const int u0 = npb >> 2;
                const int tb = text[b * STEPS + s];
                const float* gr = gbuf + rl * 36 + q * 8;
                float4 g0 = *(const float4*)gr;
                float4 g1 = *(const float4*)(gr + 4);
                float vi0 = g0.x + bias2r[npb + 0] + woh[(npb + 0) * NCLS + tb];
                float vf0 = g0.y + bias2r[npb + 1] + woh[(npb + 1) * NCLS + tb];
                float vg0 = g0.z + bias2r[npb + 2] + woh[(npb + 2) * NCLS + tb];
                float vo0 = g0.w + bias2r[npb + 3] + woh[(npb + 3) * NCLS + tb];
                float vi1 = g1.x + bias2r[npb + 4] + woh[(npb + 4) * NCLS + tb];
                float vf1 = g1.y + bias2r[npb + 5] + woh[(npb + 5) * NCLS + tb];
                float vg1 = g1.z + bias2r[npb + 6] + woh[(npb + 6) * NCLS + tb];
                float vo1 = g1.w + bias2r[npb + 7] + woh[(npb + 7) * NCLS + tb];
                float cn0 = sigmoid_f(vf0) * c0 + sigmoid_f(vi0) * tanh_f(vg0);
                float cn1 = sigmoid_f(vf1) * c1 + sigmoid_f(vi1) * tanh_f(vg1);
                c0 = cn0; c1 = cn1;
                float hn0 = sigmoid_f(vo0) * tanh_f(cn0);
                float hn1 = sigmoid_f(vo1) * tanh_f(cn1);
                unsigned hp2 = ((unsigned)f2bf(hn1) << 16) | (unsigned)f2bf(hn0);
                astore((unsigned*)(A2nxt + (size_t)b * 1024 + 512 + u0), hp2);  // coherent h
                *(unsigned*)(hseq + ((size_t)s * BATCH + b) * 512 + u0) = hp2;  // post-kernel only
            }
        }

        // ---- phase 3: hp = h_new @ w_h2h^T + b  (32x32 tile, K split over wave layers) ----
        if (s + 1 < STEPS) {
            gbar(bar, bid);
            {
                const int wi = wid & 3, kl = wid >> 2;
                const int tm = (wi >> 1) * 16, tn = (wi & 1) * 16;
                const int m0 = m3 * 32, nc = n3 * 32;
                const unsigned long long* Ab = (const unsigned long long*)
                    (A2nxt + (size_t)(m0 + tm + (lane & 15)) * 1024 + 512 + kl * 256 + (lane >> 4) * 8);
                const unsigned short* lbr = lB3 + (tn + (lane & 15)) * 520 + kl * 256 + (lane >> 4) * 8;
                unsigned long long a0v[8], a1v[8];
                #pragma unroll
                for (int kc = 0; kc < 8; ++kc) {
                    a0v[kc] = aload64(Ab + kc * 8);
                    a1v[kc] = aload64(Ab + kc * 8 + 1);
                }
                f32x4 acc = {};
                #pragma unroll
                for (int kc = 0; kc < 8; ++kc) {
                    bf16x8 af = mk_frag(a0v[kc], a1v[kc]);
                    bf16x8 bf = *(const bf16x8*)(lbr + kc * 32);
                    acc = __builtin_amdgcn_mfma_f32_16x16x32_bf16(af, bf, acc, 0, 0, 0);
                }
                float* pbuf = (float*)scr;   // [4][16][17]
                if (kl == 1) {
                    #pragma unroll
                    for (int r = 0; r < 4; r++)
                        pbuf[wi * 272 + ((lane >> 4) * 4 + r) * 17 + (lane & 15)] = acc[r];
                }
                __syncthreads();
                if (kl == 0) {
                    #pragma unroll
                    for (int r = 0; r < 4; r++) {
                        int row = (lane >> 4) * 4 + r, col = lane & 15;
                        float v = acc[r] + pbuf[wi * 272 + row * 17 + col] + b_h2h[nc + tn + col];
                        astoref(hp32 + (size_t)(m0 + tm + row) * 512 + nc + tn + col, v);
                    }
                }
            }
            gbar(bar, bid);
        }
    }
}

// ---------------- host ----------------
extern "C" void kernel_launch(void* const* d_in, const int* in_sizes, int n_in,
                              void* d_out, int out_size, void* d_ws, size_t ws_size,
                              hipStream_t stream) {
    (void)in_sizes; (void)n_in; (void)out_size; (void)ws_size;
    const float* enc_f   = (const float*)d_in[0];
    const int*   text    = (const int*)d_in[1];
    const float* w_i2h   = (const float*)d_in[2];
    const float* w_h2h   = (const float*)d_in[3];
    const float* b_h2h   = (const float*)d_in[4];
    const float* w_score = (const float*)d_in[5];
    const float* w_ih    = (const float*)d_in[6];
    const float* w_hh    = (const float*)d_in[7];
    const float* b_ih    = (const float*)d_in[8];
    const float* b_hh    = (const float*)d_in[9];
    const float* w_gen   = (const float*)d_in[10];
    const float* b_gen   = (const float*)d_in[11];
    float* out = (float*)d_out;

    char* ws = (char*)d_ws;
    const unsigned short* Hp     = (const unsigned short*)(ws + HP_OFF);
    unsigned short*       Hp_w   = (unsigned short*)(ws + HP_OFF);
    const unsigned short* encb   = (const unsigned short*)(ws + ENC_OFF);
    unsigned short*       encb_w = (unsigned short*)(ws + ENC_OFF);
    unsigned short*       A2     = (unsigned short*)(ws + A2_OFF);
    float*                hp32   = (float*)(ws + HP32_OFF);
    const unsigned short* B2r    = (const unsigned short*)(ws + B2R_OFF);
    unsigned short*       B2r_w  = (unsigned short*)(ws + B2R_OFF);
    unsigned short*       wi2hb  = (unsigned short*)(ws + WI2H_OFF);
    const unsigned short* B3     = (const unsigned short*)(ws + B3_OFF);
    unsigned short*       B3_w   = (unsigned short*)(ws + B3_OFF);
    const float*          woh    = (const float*)(ws + WOH_OFF);
    float*                woh_w  = (float*)(ws + WOH_OFF);
    const float*          bias2r = (const float*)(ws + BIAS_OFF);
    float*                bias2r_w = (float*)(ws + BIAS_OFF);
    unsigned short*       hseq   = (unsigned short*)(ws + HSEQ_OFF);
    unsigned*             bar    = (unsigned*)(ws + BAR_OFF);

    conv_bf16_kernel<<<2048, 256, 0, stream>>>(enc_f, encb_w, BATCH * TENC * DIN / 4);
    conv_bf16_kernel<<<256, 256, 0, stream>>>(w_i2h, wi2hb, HDIM * DIN / 4);
    build_b2r_kernel<<<NG, 256, 0, stream>>>(w_ih, w_hh, b_ih, b_hh, B2r_w, woh_w, bias2r_w);
    build_b3_kernel<<<576, 256, 0, stream>>>(w_h2h, w_gen, B3_w);
    init_state_kernel<<<BATCH, 256, 0, stream>>>(hp32, A2, b_h2h, bar);

    // H_proj = enc @ w_i2h^T  (M=32768, N=512, K=512)
    gemm_bf16out_kernel<<<dim3(BATCH * TENC / 128, HDIM / 128), 256, 0, stream>>>(
        encb, DIN, wi2hb, DIN, Hp_w, HDIM, DIN);

    // cooperative decode: all 26 steps in one launch (persistent weights in LDS)
    {
        void* args[13] = {
            (void*)&Hp, (void*)&encb, (void*)&A2, (void*)&hp32,
            (void*)&B2r, (void*)&bias2r, (void*)&woh, (void*)&B3,
            (void*)&b_h2h, (void*)&w_score, (void*)&text, (void*)&hseq, (void*)&bar
        };
        hipLaunchCooperativeKernel((const void*)decode_kernel, dim3(256), dim3(512),
                                   args, 0, stream);
    }

    // probs = hseq @ [w_gen;0]^T + b_gen  (M = S*B = 13312, N = 64, K = 512)
    probs_kernel<<<dim3(STEPS * BATCH / 64), 256, 0, stream>>>(
        hseq, B3 + (size_t)512 * 512, b_gen, out);
}